// Round 1
// baseline (1983.502 us; speedup 1.0000x reference)
//
#include <hip/hip_runtime.h>
#include <math.h>

// ---------------- problem constants ----------------
#define D     256
#define NH    8
#define HDIM  32
#define NL    4
#define NPT   4
#define DFF   1024
#define BB    2
#define LT    20
#define LQ    20197
#define NROWS (BB*LQ)                 // 40394
#define SFL   ((size_t)NROWS * D)     // 10,340,864 floats per N x 256 buffer

// GEMM tiling
#define MT   64
#define NT   64
#define KT   32
#define LSTR 68   // padded LDS row stride (floats), keeps float4 alignment, <=2-way read conflicts

// =====================================================================
// Generic fp32 GEMM:  C[M,Nout] = A[M,K] @ W[Nout,K]^T + bias  (optional relu)
// 256 threads, 64x64 tile, 4x4 micro-tile, K-chunks of 32 staged in LDS.
// =====================================================================
__global__ __launch_bounds__(256) void gemm_bt(const float* __restrict__ A,
                                               const float* __restrict__ W,
                                               const float* __restrict__ bias,
                                               float* __restrict__ C,
                                               int M, int Nout, int K, int relu)
{
    __shared__ float As[KT][LSTR];
    __shared__ float Ws[KT][LSTR];
    const int tid  = threadIdx.x;
    const int row0 = blockIdx.x * MT;
    const int n0   = blockIdx.y * NT;
    const int tx   = tid & 15;      // 0..15 -> n micro
    const int ty   = tid >> 4;      // 0..15 -> m micro
    const int mloc = tid >> 2;      // 0..63  loader row
    const int kq   = (tid & 3) << 3; // 0,8,16,24 loader k-offset

    const int  arow = row0 + mloc;
    const bool aok  = arow < M;
    const float* Ap = A + (size_t)arow * K + kq;
    const float* Wp = W + (size_t)(n0 + mloc) * K + kq;

    float acc[4][4];
#pragma unroll
    for (int i = 0; i < 4; ++i)
#pragma unroll
        for (int j = 0; j < 4; ++j) acc[i][j] = 0.f;

    for (int k0 = 0; k0 < K; k0 += KT) {
        float4 a0 = make_float4(0.f,0.f,0.f,0.f), a1 = a0;
        if (aok) {
            a0 = *(const float4*)(Ap + k0);
            a1 = *(const float4*)(Ap + k0 + 4);
        }
        const float4 w0 = *(const float4*)(Wp + k0);
        const float4 w1 = *(const float4*)(Wp + k0 + 4);
        __syncthreads();
        As[kq+0][mloc]=a0.x; As[kq+1][mloc]=a0.y; As[kq+2][mloc]=a0.z; As[kq+3][mloc]=a0.w;
        As[kq+4][mloc]=a1.x; As[kq+5][mloc]=a1.y; As[kq+6][mloc]=a1.z; As[kq+7][mloc]=a1.w;
        Ws[kq+0][mloc]=w0.x; Ws[kq+1][mloc]=w0.y; Ws[kq+2][mloc]=w0.z; Ws[kq+3][mloc]=w0.w;
        Ws[kq+4][mloc]=w1.x; Ws[kq+5][mloc]=w1.y; Ws[kq+6][mloc]=w1.z; Ws[kq+7][mloc]=w1.w;
        __syncthreads();
#pragma unroll
        for (int kk = 0; kk < KT; ++kk) {
            const float4 av = *(const float4*)(&As[kk][ty << 2]);
            const float4 wv = *(const float4*)(&Ws[kk][tx << 2]);
            const float ar[4] = {av.x, av.y, av.z, av.w};
            const float wr[4] = {wv.x, wv.y, wv.z, wv.w};
#pragma unroll
            for (int i = 0; i < 4; ++i)
#pragma unroll
                for (int j = 0; j < 4; ++j)
                    acc[i][j] = fmaf(ar[i], wr[j], acc[i][j]);
        }
    }

    const float4 bv = *(const float4*)(bias + n0 + (tx << 2));
#pragma unroll
    for (int i = 0; i < 4; ++i) {
        const int row = row0 + (ty << 2) + i;
        if (row < M) {
            float4 o;
            o.x = acc[i][0] + bv.x; o.y = acc[i][1] + bv.y;
            o.z = acc[i][2] + bv.z; o.w = acc[i][3] + bv.w;
            if (relu) {
                o.x = fmaxf(o.x, 0.f); o.y = fmaxf(o.y, 0.f);
                o.z = fmaxf(o.z, 0.f); o.w = fmaxf(o.w, 0.f);
            }
            *(float4*)(C + (size_t)row * Nout + n0 + (tx << 2)) = o;
        }
    }
}

// ---------------------------------------------------------------------
// elementwise: o = a + b   (float4, exact count)
// ---------------------------------------------------------------------
__global__ __launch_bounds__(256) void add_vec4(const float4* __restrict__ a,
                                                const float4* __restrict__ b,
                                                float4* __restrict__ o, int n4)
{
    const int i = blockIdx.x * 256 + threadIdx.x;
    if (i < n4) {
        const float4 x = a[i], y = b[i];
        o[i] = make_float4(x.x + y.x, x.y + y.y, x.z + y.z, x.w + y.w);
    }
}

// ---------------------------------------------------------------------
// softmax over groups of 16 (attention weights), in-place
// ---------------------------------------------------------------------
__global__ __launch_bounds__(256) void softmax16(float* __restrict__ aw, int total)
{
    const int i = blockIdx.x * 256 + threadIdx.x;
    if (i >= total) return;
    float* p = aw + (size_t)i * 16;
    float v[16];
    float m = -1e30f;
#pragma unroll
    for (int j = 0; j < 16; ++j) { v[j] = p[j]; m = fmaxf(m, v[j]); }
    float s = 0.f;
#pragma unroll
    for (int j = 0; j < 16; ++j) { v[j] = __expf(v[j] - m); s += v[j]; }
    const float inv = 1.f / s;
#pragma unroll
    for (int j = 0; j < 16; ++j) p[j] = v[j] * inv;
}

// ---------------------------------------------------------------------
// multi-scale deformable sampling core. one block per (b,query) row,
// thread = (head h = tid>>5, channel d = tid&31); col h*32+d == tid.
// ---------------------------------------------------------------------
__global__ __launch_bounds__(256) void msdeform(const float* __restrict__ value,
                                                const float* __restrict__ offs,
                                                const float* __restrict__ aw,
                                                const float* __restrict__ refp,
                                                float* __restrict__ out)
{
    const int Hs[4]  = {100, 50, 25, 13};
    const int Wsd[4] = {152, 76, 38, 19};
    const int St[4]  = {0, 15200, 19000, 19950};
    const int row = blockIdx.x;
    const int b   = row / LQ;
    const int tid = threadIdx.x;
    const int h   = tid >> 5;
    const float* vbase = value + (size_t)b * LQ * D + tid;
    float acc = 0.f;
#pragma unroll
    for (int l = 0; l < 4; ++l) {
        const int   Wi = Wsd[l], Hi = Hs[l], s = St[l];
        const float Wf = (float)Wi, Hf = (float)Hi;
        const float rx = refp[((size_t)row * NL + l) * 2 + 0];
        const float ry = refp[((size_t)row * NL + l) * 2 + 1];
#pragma unroll
        for (int p = 0; p < 4; ++p) {
            const int oi = row * D + ((h * NL + l) * NPT + p) * 2;
            const float ox  = offs[oi];
            const float oy  = offs[oi + 1];
            const float wap = aw[(size_t)row * (NH*NL*NPT) + h*(NL*NPT) + l*NPT + p];
            const float locx = rx + ox / Wf;
            const float locy = ry + oy / Hf;
            const float x = locx * Wf - 0.5f;
            const float y = locy * Hf - 0.5f;
            const float x0f = floorf(x), y0f = floorf(y);
            const float lx = x - x0f, ly = y - y0f;
            const int x0 = (int)x0f, y0 = (int)y0f;
            const float wts[4] = {(1.f-lx)*(1.f-ly), lx*(1.f-ly), (1.f-lx)*ly, lx*ly};
            const int xs[4] = {x0, x0+1, x0,   x0+1};
            const int ys[4] = {y0, y0,   y0+1, y0+1};
            float smp = 0.f;
#pragma unroll
            for (int c = 0; c < 4; ++c) {
                const int xi = xs[c], yi = ys[c];
                if (xi >= 0 && xi < Wi && yi >= 0 && yi < Hi)
                    smp = fmaf(wts[c], vbase[(size_t)(s + yi * Wi + xi) * D], smp);
            }
            acc = fmaf(wap, smp, acc);
        }
    }
    out[(size_t)row * D + tid] = acc;
}

// ---------------------------------------------------------------------
// out = LayerNorm(a + b) * g + beta  over D=256, one block per row.
// Safe for out aliasing a or b (reads complete before writes).
// ---------------------------------------------------------------------
__global__ __launch_bounds__(256) void add_ln(const float* __restrict__ a,
                                              const float* __restrict__ b,
                                              const float* __restrict__ g,
                                              const float* __restrict__ be,
                                              float* __restrict__ out)
{
    __shared__ float red[256];
    const int row = blockIdx.x, t = threadIdx.x;
    const size_t base = (size_t)row * D;
    const float v = a[base + t] + b[base + t];
    red[t] = v; __syncthreads();
    for (int s = 128; s > 0; s >>= 1) { if (t < s) red[t] += red[t + s]; __syncthreads(); }
    const float mean = red[0] * (1.f / D);
    __syncthreads();
    const float dv = v - mean;
    red[t] = dv * dv; __syncthreads();
    for (int s = 128; s > 0; s >>= 1) { if (t < s) red[t] += red[t + s]; __syncthreads(); }
    const float var = red[0] * (1.f / D);
    out[base + t] = dv * rsqrtf(var + 1e-5f) * g[t] + be[t];
}

// ---------------------------------------------------------------------
// text K/V projections: 40 rows, one block per row.
// ---------------------------------------------------------------------
__global__ __launch_bounds__(256) void text_kv(const float* __restrict__ text,
                                               const float* __restrict__ ipw,
                                               const float* __restrict__ ipb,
                                               float* __restrict__ kh,
                                               float* __restrict__ vh)
{
    __shared__ float ts[D];
    const int row = blockIdx.x, t = threadIdx.x;
    ts[t] = text[(size_t)row * D + t];
    __syncthreads();
    const float* wk = ipw + (size_t)(D + t) * D;
    const float* wv = ipw + (size_t)(2 * D + t) * D;
    float sk = ipb[D + t], sv = ipb[2 * D + t];
    for (int k = 0; k < D; ++k) {
        sk = fmaf(ts[k], wk[k], sk);
        sv = fmaf(ts[k], wv[k], sv);
    }
    kh[(size_t)row * D + t] = sk;
    vh[(size_t)row * D + t] = sv;
}

// ---------------------------------------------------------------------
// cross-attention to text (LT=20 keys). one block per query row.
// thread = (head h, channel d). scores in LDS, per-thread softmax over 20.
// ---------------------------------------------------------------------
__global__ __launch_bounds__(256) void text_attn(const float* __restrict__ qh,
                                                 const float* __restrict__ kh,
                                                 const float* __restrict__ vh,
                                                 float* __restrict__ ctx)
{
    __shared__ float qs[D];
    __shared__ float sc[NH][LT];
    const int row = blockIdx.x, t = threadIdx.x;
    const int b = row / LQ;
    const int h = t >> 5, d = t & 31;
    qs[t] = qh[(size_t)row * D + t];
    __syncthreads();
    if (d < LT) {
        const float* kr = kh + (size_t)(b * LT + d) * D + h * HDIM;
        float s = 0.f;
#pragma unroll
        for (int dd = 0; dd < HDIM; ++dd) s = fmaf(qs[h * HDIM + dd], kr[dd], s);
        sc[h][d] = s * 0.17677669529663687f;   // 1/sqrt(32)
    }
    __syncthreads();
    float m = -1e30f;
#pragma unroll
    for (int k = 0; k < LT; ++k) m = fmaxf(m, sc[h][k]);
    float sum = 0.f;
#pragma unroll
    for (int k = 0; k < LT; ++k) sum += __expf(sc[h][k] - m);
    const float inv = 1.f / sum;
    float o = 0.f;
#pragma unroll
    for (int k = 0; k < LT; ++k)
        o = fmaf(__expf(sc[h][k] - m) * inv, vh[(size_t)(b * LT + k) * D + h * HDIM + d], o);
    ctx[(size_t)row * D + t] = o;
}

// ---------------------------------------------------------------------
__global__ __launch_bounds__(256) void copy_text(const float* __restrict__ text,
                                                 float* __restrict__ out)
{
    const int i = blockIdx.x * 256 + threadIdx.x;   // exact: 40 blocks * 256 = 10240
    out[i] = text[i];
}

// =====================================================================
extern "C" void kernel_launch(void* const* d_in, const int* in_sizes, int n_in,
                              void* d_out, int out_size, void* d_ws, size_t ws_size,
                              hipStream_t stream)
{
    const float* src  = (const float*)d_in[0];
    const float* pos  = (const float*)d_in[1];
    const float* refp = (const float*)d_in[2];
    // d_in[3] spatial_shapes, d_in[4] level_start_index: fixed, hardcoded
    const float* text = (const float*)d_in[5];
    // d_in[6] text_mask: unused by reference
    const float* so_w = (const float*)d_in[7];
    const float* so_b = (const float*)d_in[8];
    const float* aw_w = (const float*)d_in[9];
    const float* aw_b = (const float*)d_in[10];
    const float* vp_w = (const float*)d_in[11];
    const float* vp_b = (const float*)d_in[12];
    const float* op_w = (const float*)d_in[13];
    const float* op_b = (const float*)d_in[14];
    const float* ln1g = (const float*)d_in[15];
    const float* ln1b = (const float*)d_in[16];
    const float* ipw  = (const float*)d_in[17];
    const float* ipb  = (const float*)d_in[18];
    const float* mow  = (const float*)d_in[19];
    const float* mob  = (const float*)d_in[20];
    const float* ln3g = (const float*)d_in[21];
    const float* ln3b = (const float*)d_in[22];
    const float* l1w  = (const float*)d_in[23];
    const float* l1b  = (const float*)d_in[24];
    const float* l2w  = (const float*)d_in[25];
    const float* l2b  = (const float*)d_in[26];
    const float* ln2g = (const float*)d_in[27];
    const float* ln2b = (const float*)d_in[28];

    float* ws   = (float*)d_ws;
    float* bufA = ws;                 // q -> ms -> q2 -> ctx -> x2
    float* bufB = ws + SFL;           // value -> (hidden part)
    float* bufC = ws + 2 * SFL;       // offs -> qh -> mha
    float* bufD = ws + 3 * SFL;       // mscore -> (hidden part)
    float* bufE = ws + 4 * SFL;       // x1 -> (hidden part)
    float* awl  = ws + 5 * SFL;       // N*128 attn-weight logits/softmax
    float* kvk  = awl + SFL / 2;      // 10240 floats
    float* kvv  = kvk + (size_t)BB * LT * D;
    float* hidden = bufB;             // spans bufB..bufE : N*1024 floats (all dead by then)
    float* outx   = (float*)d_out;    // N*256 final x  (also used as ffn scratch)
    float* outtxt = outx + SFL;       // text passthrough

    const int M = NROWS;
    const int mtiles = (M + MT - 1) / MT;   // 632
    const dim3 blk(256);
    const int n4 = (int)(SFL / 4);
    const int addgrid = (n4 + 255) / 256;

    // 1. q = src + pos -> A
    add_vec4<<<dim3(addgrid), blk, 0, stream>>>((const float4*)src, (const float4*)pos, (float4*)bufA, n4);
    // 2. value = src @ vp^T + b -> B
    gemm_bt<<<dim3(mtiles, 4), blk, 0, stream>>>(src, vp_w, vp_b, bufB, M, 256, 256, 0);
    // 3. sampling offsets = q @ so^T + b -> C
    gemm_bt<<<dim3(mtiles, 4), blk, 0, stream>>>(bufA, so_w, so_b, bufC, M, 256, 256, 0);
    // 4. attn-weight logits = q @ aw^T + b -> awl
    gemm_bt<<<dim3(mtiles, 2), blk, 0, stream>>>(bufA, aw_w, aw_b, awl, M, 128, 256, 0);
    // 5. softmax over 16 per (row,head)
    {
        const int tot = M * NH;
        softmax16<<<dim3((tot + 255) / 256), blk, 0, stream>>>(awl, tot);
    }
    // 6. deformable sampling -> D
    msdeform<<<dim3(M), blk, 0, stream>>>(bufB, bufC, awl, refp, bufD);
    // 7. ms = mscore @ op^T + b -> A
    gemm_bt<<<dim3(mtiles, 4), blk, 0, stream>>>(bufD, op_w, op_b, bufA, M, 256, 256, 0);
    // 8. x1 = LN(src + ms) -> E
    add_ln<<<dim3(M), blk, 0, stream>>>(src, bufA, ln1g, ln1b, bufE);
    // 9. q2 = x1 + pos -> A
    add_vec4<<<dim3(addgrid), blk, 0, stream>>>((const float4*)bufE, (const float4*)pos, (float4*)bufA, n4);
    // 10. text K/V
    text_kv<<<dim3(BB * LT), blk, 0, stream>>>(text, ipw, ipb, kvk, kvv);
    // 11. qh = q2 @ wq^T + bq -> C
    gemm_bt<<<dim3(mtiles, 4), blk, 0, stream>>>(bufA, ipw, ipb, bufC, M, 256, 256, 0);
    // 12. ctx = attn(qh, kh, vh) -> A
    text_attn<<<dim3(M), blk, 0, stream>>>(bufC, kvk, kvv, bufA);
    // 13. mha = ctx @ mow^T + b -> C
    gemm_bt<<<dim3(mtiles, 4), blk, 0, stream>>>(bufA, mow, mob, bufC, M, 256, 256, 0);
    // 14. x2 = LN(x1 + mha) -> A
    add_ln<<<dim3(M), blk, 0, stream>>>(bufE, bufC, ln3g, ln3b, bufA);
    // 15. hidden = relu(x2 @ l1^T + b) -> [bufB..bufE]
    gemm_bt<<<dim3(mtiles, 16), blk, 0, stream>>>(bufA, l1w, l1b, hidden, M, 1024, 256, 1);
    // 16. ffn = hidden @ l2^T + b -> d_out (scratch use)
    gemm_bt<<<dim3(mtiles, 4), blk, 0, stream>>>(hidden, l2w, l2b, outx, M, 256, 1024, 0);
    // 17. x3 = LN(x2 + ffn) -> d_out (in-place safe)
    add_ln<<<dim3(M), blk, 0, stream>>>(bufA, outx, ln2g, ln2b, outx);
    // 18. text passthrough output
    copy_text<<<dim3(BB * LT), blk, 0, stream>>>(text, outtxt);
}

// Round 2
// 1674.351 us; speedup vs baseline: 1.1846x; 1.1846x over previous
//
#include <hip/hip_runtime.h>
#include <math.h>

// ---------------- problem constants ----------------
#define D     256
#define NH    8
#define HDIM  32
#define NL    4
#define NPT   4
#define DFF   1024
#define BB    2
#define LT    20
#define LQ    20197
#define NROWS (BB*LQ)                 // 40394
#define SFL   ((size_t)NROWS * D)     // floats per N x 256 buffer

// GEMM tiling: 128x128 block tile, 8x8 micro-tile, K-chunk 16
#define MT   128
#define NT   128
#define KT   16
#define LSTR 132   // padded LDS row stride (floats)

// =====================================================================
// fp32 GEMM:  C[M,Nout] = A[M,K] @ W[Nout,K]^T + bias  (optional relu)
// 256 threads, 128x128 tile, 8x8 micro-tile. Nout must be multiple of 128.
// =====================================================================
__global__ __launch_bounds__(256) void gemm_bt(const float* __restrict__ A,
                                               const float* __restrict__ W,
                                               const float* __restrict__ bias,
                                               float* __restrict__ C,
                                               int M, int Nout, int K, int relu)
{
    __shared__ float As[KT][LSTR];
    __shared__ float Ws[KT][LSTR];
    const int tid  = threadIdx.x;
    const int row0 = blockIdx.x * MT;
    const int n0   = blockIdx.y * NT;
    const int tx   = tid & 15;       // n micro (8 cols)
    const int ty   = tid >> 4;       // m micro (8 rows)
    const int lrow = tid >> 1;       // loader row 0..127
    const int kq   = (tid & 1) << 3; // loader k-offset: 0 or 8

    const int  arow = row0 + lrow;
    const bool aok  = arow < M;
    const float* Ap = A + (size_t)arow * K + kq;
    const float* Wp = W + (size_t)(n0 + lrow) * K + kq;

    float acc[8][8];
#pragma unroll
    for (int i = 0; i < 8; ++i)
#pragma unroll
        for (int j = 0; j < 8; ++j) acc[i][j] = 0.f;

    for (int k0 = 0; k0 < K; k0 += KT) {
        float4 a0 = make_float4(0.f,0.f,0.f,0.f), a1 = a0;
        if (aok) {
            a0 = *(const float4*)(Ap + k0);
            a1 = *(const float4*)(Ap + k0 + 4);
        }
        const float4 w0 = *(const float4*)(Wp + k0);
        const float4 w1 = *(const float4*)(Wp + k0 + 4);
        __syncthreads();
        As[kq+0][lrow]=a0.x; As[kq+1][lrow]=a0.y; As[kq+2][lrow]=a0.z; As[kq+3][lrow]=a0.w;
        As[kq+4][lrow]=a1.x; As[kq+5][lrow]=a1.y; As[kq+6][lrow]=a1.z; As[kq+7][lrow]=a1.w;
        Ws[kq+0][lrow]=w0.x; Ws[kq+1][lrow]=w0.y; Ws[kq+2][lrow]=w0.z; Ws[kq+3][lrow]=w0.w;
        Ws[kq+4][lrow]=w1.x; Ws[kq+5][lrow]=w1.y; Ws[kq+6][lrow]=w1.z; Ws[kq+7][lrow]=w1.w;
        __syncthreads();
#pragma unroll
        for (int kk = 0; kk < KT; ++kk) {
            const float4 av0 = *(const float4*)(&As[kk][ty << 3]);
            const float4 av1 = *(const float4*)(&As[kk][(ty << 3) + 4]);
            const float4 wv0 = *(const float4*)(&Ws[kk][tx << 3]);
            const float4 wv1 = *(const float4*)(&Ws[kk][(tx << 3) + 4]);
            const float ar[8] = {av0.x,av0.y,av0.z,av0.w, av1.x,av1.y,av1.z,av1.w};
            const float wr[8] = {wv0.x,wv0.y,wv0.z,wv0.w, wv1.x,wv1.y,wv1.z,wv1.w};
#pragma unroll
            for (int i = 0; i < 8; ++i)
#pragma unroll
                for (int j = 0; j < 8; ++j)
                    acc[i][j] = fmaf(ar[i], wr[j], acc[i][j]);
        }
    }

    const float4 bv0 = *(const float4*)(bias + n0 + (tx << 3));
    const float4 bv1 = *(const float4*)(bias + n0 + (tx << 3) + 4);
    const float br[8] = {bv0.x,bv0.y,bv0.z,bv0.w, bv1.x,bv1.y,bv1.z,bv1.w};
#pragma unroll
    for (int i = 0; i < 8; ++i) {
        const int row = row0 + (ty << 3) + i;
        if (row < M) {
            float o[8];
#pragma unroll
            for (int j = 0; j < 8; ++j) {
                o[j] = acc[i][j] + br[j];
                if (relu) o[j] = fmaxf(o[j], 0.f);
            }
            float* cp = C + (size_t)row * Nout + n0 + (tx << 3);
            *(float4*)(cp)     = make_float4(o[0],o[1],o[2],o[3]);
            *(float4*)(cp + 4) = make_float4(o[4],o[5],o[6],o[7]);
        }
    }
}

// ---------------------------------------------------------------------
__global__ __launch_bounds__(256) void add_vec4(const float4* __restrict__ a,
                                                const float4* __restrict__ b,
                                                float4* __restrict__ o, int n4)
{
    const int i = blockIdx.x * 256 + threadIdx.x;
    if (i < n4) {
        const float4 x = a[i], y = b[i];
        o[i] = make_float4(x.x + y.x, x.y + y.y, x.z + y.z, x.w + y.w);
    }
}

// ---------------------------------------------------------------------
// softmax over groups of 16 (attention weights), in-place
// ---------------------------------------------------------------------
__global__ __launch_bounds__(256) void softmax16(float* __restrict__ aw, int total)
{
    const int i = blockIdx.x * 256 + threadIdx.x;
    if (i >= total) return;
    float* p = aw + (size_t)i * 16;
    float v[16];
    float m = -1e30f;
#pragma unroll
    for (int j = 0; j < 16; ++j) { v[j] = p[j]; m = fmaxf(m, v[j]); }
    float s = 0.f;
#pragma unroll
    for (int j = 0; j < 16; ++j) { v[j] = __expf(v[j] - m); s += v[j]; }
    const float inv = 1.f / s;
#pragma unroll
    for (int j = 0; j < 16; ++j) p[j] = v[j] * inv;
}

// ---------------------------------------------------------------------
// multi-scale deformable sampling, one WAVE per query.
// lane = h*8 + quad; each lane owns 4 contiguous channels (float4).
// block = 256 threads = 4 queries.
// ---------------------------------------------------------------------
__global__ __launch_bounds__(256) void msdeform(const float* __restrict__ value,
                                                const float* __restrict__ offs,
                                                const float* __restrict__ aw,
                                                const float* __restrict__ refp,
                                                float* __restrict__ out)
{
    const int Hs[4]  = {100, 50, 25, 13};
    const int Wsd[4] = {152, 76, 38, 19};
    const int St[4]  = {0, 15200, 19000, 19950};
    const int tid  = threadIdx.x;
    const int lane = tid & 63;
    const int row  = blockIdx.x * 4 + (tid >> 6);
    if (row >= NROWS) return;             // whole wave exits together
    const int b  = row / LQ;
    const int h  = lane >> 3;
    const int ch = (h << 5) + ((lane & 7) << 2);   // h*32 + quad*4
    const float* vbase = value + (size_t)b * LQ * D + ch;
    float4 acc = make_float4(0.f,0.f,0.f,0.f);
#pragma unroll
    for (int l = 0; l < 4; ++l) {
        const int   Wi = Wsd[l], Hi = Hs[l], s = St[l];
        const float Wf = (float)Wi, Hf = (float)Hi;
        const float rx = refp[((size_t)row * NL + l) * 2 + 0];
        const float ry = refp[((size_t)row * NL + l) * 2 + 1];
#pragma unroll
        for (int p = 0; p < 4; ++p) {
            const int oi = row * D + ((h * NL + l) * NPT + p) * 2;
            const float ox  = offs[oi];
            const float oy  = offs[oi + 1];
            const float wap = aw[(size_t)row * (NH*NL*NPT) + h*(NL*NPT) + l*NPT + p];
            const float x = (rx + ox / Wf) * Wf - 0.5f;
            const float y = (ry + oy / Hf) * Hf - 0.5f;
            const float x0f = floorf(x), y0f = floorf(y);
            const float lx = x - x0f, ly = y - y0f;
            const int x0 = (int)x0f, y0 = (int)y0f;
            const float wts[4] = {(1.f-lx)*(1.f-ly), lx*(1.f-ly), (1.f-lx)*ly, lx*ly};
            const int xs[4] = {x0, x0+1, x0,   x0+1};
            const int ys[4] = {y0, y0,   y0+1, y0+1};
            float4 smp = make_float4(0.f,0.f,0.f,0.f);
#pragma unroll
            for (int c = 0; c < 4; ++c) {
                const int xi = xs[c], yi = ys[c];
                if (xi >= 0 && xi < Wi && yi >= 0 && yi < Hi) {
                    const float4 g = *(const float4*)(vbase + (size_t)(s + yi * Wi + xi) * D);
                    smp.x = fmaf(wts[c], g.x, smp.x);
                    smp.y = fmaf(wts[c], g.y, smp.y);
                    smp.z = fmaf(wts[c], g.z, smp.z);
                    smp.w = fmaf(wts[c], g.w, smp.w);
                }
            }
            acc.x = fmaf(wap, smp.x, acc.x);
            acc.y = fmaf(wap, smp.y, acc.y);
            acc.z = fmaf(wap, smp.z, acc.z);
            acc.w = fmaf(wap, smp.w, acc.w);
        }
    }
    *(float4*)(out + (size_t)row * D + ch) = acc;
}

// ---------------------------------------------------------------------
// out = LayerNorm(a + b) * g + beta  over D=256, one block per row.
// ---------------------------------------------------------------------
__global__ __launch_bounds__(256) void add_ln(const float* __restrict__ a,
                                              const float* __restrict__ b,
                                              const float* __restrict__ g,
                                              const float* __restrict__ be,
                                              float* __restrict__ out)
{
    __shared__ float red[256];
    const int row = blockIdx.x, t = threadIdx.x;
    const size_t base = (size_t)row * D;
    const float v = a[base + t] + b[base + t];
    red[t] = v; __syncthreads();
    for (int s = 128; s > 0; s >>= 1) { if (t < s) red[t] += red[t + s]; __syncthreads(); }
    const float mean = red[0] * (1.f / D);
    __syncthreads();
    const float dv = v - mean;
    red[t] = dv * dv; __syncthreads();
    for (int s = 128; s > 0; s >>= 1) { if (t < s) red[t] += red[t + s]; __syncthreads(); }
    const float var = red[0] * (1.f / D);
    out[base + t] = dv * rsqrtf(var + 1e-5f) * g[t] + be[t];
}

// ---------------------------------------------------------------------
__global__ __launch_bounds__(256) void text_kv(const float* __restrict__ text,
                                               const float* __restrict__ ipw,
                                               const float* __restrict__ ipb,
                                               float* __restrict__ kh,
                                               float* __restrict__ vh)
{
    __shared__ float ts[D];
    const int row = blockIdx.x, t = threadIdx.x;
    ts[t] = text[(size_t)row * D + t];
    __syncthreads();
    const float* wk = ipw + (size_t)(D + t) * D;
    const float* wv = ipw + (size_t)(2 * D + t) * D;
    float sk = ipb[D + t], sv = ipb[2 * D + t];
    for (int k = 0; k < D; ++k) {
        sk = fmaf(ts[k], wk[k], sk);
        sv = fmaf(ts[k], wv[k], sv);
    }
    kh[(size_t)row * D + t] = sk;
    vh[(size_t)row * D + t] = sv;
}

// ---------------------------------------------------------------------
__global__ __launch_bounds__(256) void text_attn(const float* __restrict__ qh,
                                                 const float* __restrict__ kh,
                                                 const float* __restrict__ vh,
                                                 float* __restrict__ ctx)
{
    __shared__ float qs[D];
    __shared__ float sc[NH][LT];
    const int row = blockIdx.x, t = threadIdx.x;
    const int b = row / LQ;
    const int h = t >> 5, d = t & 31;
    qs[t] = qh[(size_t)row * D + t];
    __syncthreads();
    if (d < LT) {
        const float* kr = kh + (size_t)(b * LT + d) * D + h * HDIM;
        float s = 0.f;
#pragma unroll
        for (int dd = 0; dd < HDIM; ++dd) s = fmaf(qs[h * HDIM + dd], kr[dd], s);
        sc[h][d] = s * 0.17677669529663687f;   // 1/sqrt(32)
    }
    __syncthreads();
    float m = -1e30f;
#pragma unroll
    for (int k = 0; k < LT; ++k) m = fmaxf(m, sc[h][k]);
    float sum = 0.f;
#pragma unroll
    for (int k = 0; k < LT; ++k) sum += __expf(sc[h][k] - m);
    const float inv = 1.f / sum;
    float o = 0.f;
#pragma unroll
    for (int k = 0; k < LT; ++k)
        o = fmaf(__expf(sc[h][k] - m) * inv, vh[(size_t)(b * LT + k) * D + h * HDIM + d], o);
    ctx[(size_t)row * D + t] = o;
}

// ---------------------------------------------------------------------
__global__ __launch_bounds__(256) void copy_text(const float* __restrict__ text,
                                                 float* __restrict__ out)
{
    const int i = blockIdx.x * 256 + threadIdx.x;   // 40 blocks * 256 = 10240 exact
    out[i] = text[i];
}

// =====================================================================
extern "C" void kernel_launch(void* const* d_in, const int* in_sizes, int n_in,
                              void* d_out, int out_size, void* d_ws, size_t ws_size,
                              hipStream_t stream)
{
    const float* src  = (const float*)d_in[0];
    const float* pos  = (const float*)d_in[1];
    const float* refp = (const float*)d_in[2];
    const float* text = (const float*)d_in[5];
    const float* so_w = (const float*)d_in[7];
    const float* so_b = (const float*)d_in[8];
    const float* aw_w = (const float*)d_in[9];
    const float* aw_b = (const float*)d_in[10];
    const float* vp_w = (const float*)d_in[11];
    const float* vp_b = (const float*)d_in[12];
    const float* op_w = (const float*)d_in[13];
    const float* op_b = (const float*)d_in[14];
    const float* ln1g = (const float*)d_in[15];
    const float* ln1b = (const float*)d_in[16];
    const float* ipw  = (const float*)d_in[17];
    const float* ipb  = (const float*)d_in[18];
    const float* mow  = (const float*)d_in[19];
    const float* mob  = (const float*)d_in[20];
    const float* ln3g = (const float*)d_in[21];
    const float* ln3b = (const float*)d_in[22];
    const float* l1w  = (const float*)d_in[23];
    const float* l1b  = (const float*)d_in[24];
    const float* l2w  = (const float*)d_in[25];
    const float* l2b  = (const float*)d_in[26];
    const float* ln2g = (const float*)d_in[27];
    const float* ln2b = (const float*)d_in[28];

    float* ws   = (float*)d_ws;
    float* bufA = ws;                 // q -> ms -> q2 -> ctx -> x2
    float* bufB = ws + SFL;           // value -> (hidden part)
    float* bufC = ws + 2 * SFL;       // offs -> qh -> mha
    float* bufD = ws + 3 * SFL;       // mscore -> (hidden part)
    float* bufE = ws + 4 * SFL;       // x1 -> (hidden part)
    float* awl  = ws + 5 * SFL;       // N*128 attn-weight logits/softmax
    float* kvk  = awl + SFL / 2;
    float* kvv  = kvk + (size_t)BB * LT * D;
    float* hidden = bufB;             // spans bufB..bufE : N*1024 floats
    float* outx   = (float*)d_out;
    float* outtxt = outx + SFL;

    const int M = NROWS;
    const int mtiles = (M + MT - 1) / MT;   // 316
    const dim3 blk(256);
    const int n4 = (int)(SFL / 4);
    const int addgrid = (n4 + 255) / 256;
    const int dgrid = (M + 3) / 4;          // msdeform: 4 queries/block

    // 1. q = src + pos -> A
    add_vec4<<<dim3(addgrid), blk, 0, stream>>>((const float4*)src, (const float4*)pos, (float4*)bufA, n4);
    // 2. value = src @ vp^T + b -> B
    gemm_bt<<<dim3(mtiles, 2), blk, 0, stream>>>(src, vp_w, vp_b, bufB, M, 256, 256, 0);
    // 3. sampling offsets = q @ so^T + b -> C
    gemm_bt<<<dim3(mtiles, 2), blk, 0, stream>>>(bufA, so_w, so_b, bufC, M, 256, 256, 0);
    // 4. attn-weight logits = q @ aw^T + b -> awl
    gemm_bt<<<dim3(mtiles, 1), blk, 0, stream>>>(bufA, aw_w, aw_b, awl, M, 128, 256, 0);
    // 5. softmax
    {
        const int tot = M * NH;
        softmax16<<<dim3((tot + 255) / 256), blk, 0, stream>>>(awl, tot);
    }
    // 6. deformable sampling -> D
    msdeform<<<dim3(dgrid), blk, 0, stream>>>(bufB, bufC, awl, refp, bufD);
    // 7. ms = mscore @ op^T + b -> A
    gemm_bt<<<dim3(mtiles, 2), blk, 0, stream>>>(bufD, op_w, op_b, bufA, M, 256, 256, 0);
    // 8. x1 = LN(src + ms) -> E
    add_ln<<<dim3(M), blk, 0, stream>>>(src, bufA, ln1g, ln1b, bufE);
    // 9. q2 = x1 + pos -> A
    add_vec4<<<dim3(addgrid), blk, 0, stream>>>((const float4*)bufE, (const float4*)pos, (float4*)bufA, n4);
    // 10. text K/V
    text_kv<<<dim3(BB * LT), blk, 0, stream>>>(text, ipw, ipb, kvk, kvv);
    // 11. qh = q2 @ wq^T + bq -> C
    gemm_bt<<<dim3(mtiles, 2), blk, 0, stream>>>(bufA, ipw, ipb, bufC, M, 256, 256, 0);
    // 12. ctx -> A
    text_attn<<<dim3(M), blk, 0, stream>>>(bufC, kvk, kvv, bufA);
    // 13. mha = ctx @ mow^T + b -> C
    gemm_bt<<<dim3(mtiles, 2), blk, 0, stream>>>(bufA, mow, mob, bufC, M, 256, 256, 0);
    // 14. x2 = LN(x1 + mha) -> A
    add_ln<<<dim3(M), blk, 0, stream>>>(bufE, bufC, ln3g, ln3b, bufA);
    // 15. hidden = relu(x2 @ l1^T + b)
    gemm_bt<<<dim3(mtiles, 8), blk, 0, stream>>>(bufA, l1w, l1b, hidden, M, 1024, 256, 1);
    // 16. ffn = hidden @ l2^T + b -> d_out (scratch)
    gemm_bt<<<dim3(mtiles, 2), blk, 0, stream>>>(hidden, l2w, l2b, outx, M, 256, 1024, 0);
    // 17. x3 = LN(x2 + ffn) -> d_out
    add_ln<<<dim3(M), blk, 0, stream>>>(bufA, outx, ln2g, ln2b, outx);
    // 18. text passthrough
    copy_text<<<dim3(BB * LT), blk, 0, stream>>>(text, outtxt);
}

// Round 3
// 1004.919 us; speedup vs baseline: 1.9738x; 1.6662x over previous
//
#include <hip/hip_runtime.h>
#include <math.h>

// ---------------- problem constants ----------------
#define D     256
#define NH    8
#define HDIM  32
#define NL    4
#define NPT   4
#define DFF   1024
#define BB    2
#define LT    20
#define LQ    20197
#define NROWS (BB*LQ)                 // 40394
#define SFL   ((size_t)NROWS * D)     // floats per N x 256 buffer

typedef __attribute__((ext_vector_type(8))) short bf16x8;
typedef __attribute__((ext_vector_type(4))) float f32x4;

__device__ __forceinline__ unsigned short f2b(float f) {
    unsigned int u = __float_as_uint(f);
    unsigned int r = (u + 0x7FFFu + ((u >> 16) & 1u)) >> 16;   // RNE
    return (unsigned short)r;
}
__device__ __forceinline__ float b2f(unsigned short u) {
    return __uint_as_float((unsigned int)u << 16);
}

#define GLDS16(g, l) __builtin_amdgcn_global_load_lds( \
    (const __attribute__((address_space(1))) unsigned int*)(g), \
    (__attribute__((address_space(3))) unsigned int*)(l), 16, 0, 0)

// =====================================================================
// bf16 MFMA GEMM:  C[M,Nout] = A[M,K](bf16) @ W[Nout,K](bf16)^T + bias
// 128x128 tile, BK=32, 4 waves (2x2 of 64x64), mfma_f32_16x16x32_bf16.
// Output fp32 (Cf) or bf16 (Cb, with optional relu). Nout%128==0, K%32==0.
// =====================================================================
__global__ __launch_bounds__(256) void gemm_mfma(const unsigned short* __restrict__ A,
                                                 const unsigned short* __restrict__ W,
                                                 const float* __restrict__ bias,
                                                 float* __restrict__ Cf,
                                                 unsigned short* __restrict__ Cb,
                                                 int M, int Nout, int K, int relu)
{
    __shared__ __align__(16) unsigned short As[128 * 32];
    __shared__ __align__(16) unsigned short Ws[128 * 32];
    const int tid  = threadIdx.x;
    const int wave = tid >> 6, lane = tid & 63;
    const int row0 = blockIdx.x * 128, n0 = blockIdx.y * 128;
    const int wm = (wave >> 1) * 64, wn = (wave & 1) * 64;

    // staging: wave covers rows [wave*32, wave*32+32) of each 128x32 tile,
    // two ops of 1KB each; lane -> row wave*32+(lane>>2)(+16), k-elems (lane&3)*8
    const int srow = (wave << 5) + (lane >> 2);
    const int kcol = (lane & 3) << 3;
    const int ar0 = min(row0 + srow,      M - 1);
    const int ar1 = min(row0 + srow + 16, M - 1);
    const unsigned short* Ap0 = A + (size_t)ar0 * K + kcol;
    const unsigned short* Ap1 = A + (size_t)ar1 * K + kcol;
    const unsigned short* Wp0 = W + (size_t)(n0 + srow) * K + kcol;
    const unsigned short* Wp1 = W + (size_t)(n0 + srow + 16) * K + kcol;
    unsigned short* lA0 = &As[(wave << 10)];          // wave*1024 elems = wave*2048 B
    unsigned short* lA1 = &As[(wave << 10) + 512];
    unsigned short* lW0 = &Ws[(wave << 10)];
    unsigned short* lW1 = &Ws[(wave << 10) + 512];

    f32x4 acc[4][4];
#pragma unroll
    for (int i = 0; i < 4; ++i)
#pragma unroll
        for (int j = 0; j < 4; ++j)
#pragma unroll
            for (int r = 0; r < 4; ++r) acc[i][j][r] = 0.f;

    const int fr = lane & 15;            // fragment row within 16x16
    const int fk = (lane >> 4) << 3;     // fragment k-offset: 0,8,16,24

    for (int k0 = 0; k0 < K; k0 += 32) {
        GLDS16(Ap0 + k0, lA0);
        GLDS16(Ap1 + k0, lA1);
        GLDS16(Wp0 + k0, lW0);
        GLDS16(Wp1 + k0, lW1);
        __syncthreads();
        bf16x8 af[4], wf[4];
#pragma unroll
        for (int t = 0; t < 4; ++t) {
            af[t] = *(const bf16x8*)&As[(wm + t * 16 + fr) * 32 + fk];
            wf[t] = *(const bf16x8*)&Ws[(wn + t * 16 + fr) * 32 + fk];
        }
#pragma unroll
        for (int i = 0; i < 4; ++i)
#pragma unroll
            for (int j = 0; j < 4; ++j)
                acc[i][j] = __builtin_amdgcn_mfma_f32_16x16x32_bf16(af[i], wf[j], acc[i][j], 0, 0, 0);
        __syncthreads();
    }

    // epilogue: C row = row0+wm+mt*16+(lane>>4)*4+r, col = n0+wn+nt*16+(lane&15)
    const int rq = (lane >> 4) << 2;
    const int cq = lane & 15;
#pragma unroll
    for (int mt = 0; mt < 4; ++mt) {
#pragma unroll
        for (int r = 0; r < 4; ++r) {
            const int row = row0 + wm + mt * 16 + rq + r;
            if (row < M) {
#pragma unroll
                for (int nt = 0; nt < 4; ++nt) {
                    const int c = n0 + wn + nt * 16 + cq;
                    float v = acc[mt][nt][r] + bias[c];
                    if (relu) v = fmaxf(v, 0.f);
                    if (Cb) Cb[(size_t)row * Nout + c] = f2b(v);
                    else    Cf[(size_t)row * Nout + c] = v;
                }
            }
        }
    }
}

// ---------------------------------------------------------------------
// batched fp32 -> bf16 weight cast (8 segments in one launch)
// ---------------------------------------------------------------------
struct W8 {
    const float* s[8];
    unsigned short* d[8];
    int n[8];
};
__global__ __launch_bounds__(256) void cast_w8(W8 w)
{
    const int seg = blockIdx.y;
    const int n = w.n[seg];
    const float* s = w.s[seg];
    unsigned short* d = w.d[seg];
    for (int i = blockIdx.x * 256 + threadIdx.x; i < n; i += gridDim.x * 256)
        d[i] = f2b(s[i]);
}

// fp32 -> bf16, vectorized (float4 -> ushort4), n4 = count/4
__global__ __launch_bounds__(256) void cast4(const float4* __restrict__ s,
                                             ushort4* __restrict__ d, int n4)
{
    const int i = blockIdx.x * 256 + threadIdx.x;
    if (i < n4) {
        const float4 v = s[i];
        d[i] = make_ushort4(f2b(v.x), f2b(v.y), f2b(v.z), f2b(v.w));
    }
}

// o_bf16 = a + b, vectorized
__global__ __launch_bounds__(256) void add2_bf(const float4* __restrict__ a,
                                               const float4* __restrict__ b,
                                               ushort4* __restrict__ o, int n4)
{
    const int i = blockIdx.x * 256 + threadIdx.x;
    if (i < n4) {
        const float4 x = a[i], y = b[i];
        o[i] = make_ushort4(f2b(x.x + y.x), f2b(x.y + y.y), f2b(x.z + y.z), f2b(x.w + y.w));
    }
}

// ---------------------------------------------------------------------
// softmax over groups of 16 (attention weights), in-place
// ---------------------------------------------------------------------
__global__ __launch_bounds__(256) void softmax16(float* __restrict__ aw, int total)
{
    const int i = blockIdx.x * 256 + threadIdx.x;
    if (i >= total) return;
    float* p = aw + (size_t)i * 16;
    float v[16];
    float m = -1e30f;
#pragma unroll
    for (int j = 0; j < 16; ++j) { v[j] = p[j]; m = fmaxf(m, v[j]); }
    float s = 0.f;
#pragma unroll
    for (int j = 0; j < 16; ++j) { v[j] = __expf(v[j] - m); s += v[j]; }
    const float inv = 1.f / s;
#pragma unroll
    for (int j = 0; j < 16; ++j) p[j] = v[j] * inv;
}

// ---------------------------------------------------------------------
// multi-scale deformable sampling, one WAVE per query; value in bf16.
// lane = h*8 + quad; each lane owns 4 channels (8 bytes bf16).
// output mscore in bf16.
// ---------------------------------------------------------------------
__global__ __launch_bounds__(256) void msdeform(const unsigned short* __restrict__ value,
                                                const float* __restrict__ offs,
                                                const float* __restrict__ aw,
                                                const float* __restrict__ refp,
                                                unsigned short* __restrict__ out)
{
    const int Hs[4]  = {100, 50, 25, 13};
    const int Wsd[4] = {152, 76, 38, 19};
    const int St[4]  = {0, 15200, 19000, 19950};
    const int tid  = threadIdx.x;
    const int lane = tid & 63;
    const int row  = blockIdx.x * 4 + (tid >> 6);
    if (row >= NROWS) return;
    const int b  = row / LQ;
    const int h  = lane >> 3;
    const int ch = (h << 5) + ((lane & 7) << 2);
    const unsigned short* vbase = value + (size_t)b * LQ * D + ch;
    float ax = 0.f, ay = 0.f, az = 0.f, awc = 0.f;
#pragma unroll
    for (int l = 0; l < 4; ++l) {
        const int   Wi = Wsd[l], Hi = Hs[l], s = St[l];
        const float Wf = (float)Wi, Hf = (float)Hi;
        const float rx = refp[((size_t)row * NL + l) * 2 + 0];
        const float ry = refp[((size_t)row * NL + l) * 2 + 1];
#pragma unroll
        for (int p = 0; p < 4; ++p) {
            const int oi = row * D + ((h * NL + l) * NPT + p) * 2;
            const float ox  = offs[oi];
            const float oy  = offs[oi + 1];
            const float wap = aw[(size_t)row * (NH*NL*NPT) + h*(NL*NPT) + l*NPT + p];
            const float x = (rx + ox / Wf) * Wf - 0.5f;
            const float y = (ry + oy / Hf) * Hf - 0.5f;
            const float x0f = floorf(x), y0f = floorf(y);
            const float lx = x - x0f, ly = y - y0f;
            const int x0 = (int)x0f, y0 = (int)y0f;
            const float wts[4] = {(1.f-lx)*(1.f-ly), lx*(1.f-ly), (1.f-lx)*ly, lx*ly};
            const int xs[4] = {x0, x0+1, x0,   x0+1};
            const int ys[4] = {y0, y0,   y0+1, y0+1};
            float sx = 0.f, sy = 0.f, sz = 0.f, sw = 0.f;
#pragma unroll
            for (int c = 0; c < 4; ++c) {
                const int xi = xs[c], yi = ys[c];
                if (xi >= 0 && xi < Wi && yi >= 0 && yi < Hi) {
                    const ushort4 g = *(const ushort4*)(vbase + (size_t)(s + yi * Wi + xi) * D);
                    sx = fmaf(wts[c], b2f(g.x), sx);
                    sy = fmaf(wts[c], b2f(g.y), sy);
                    sz = fmaf(wts[c], b2f(g.z), sz);
                    sw = fmaf(wts[c], b2f(g.w), sw);
                }
            }
            ax = fmaf(wap, sx, ax); ay = fmaf(wap, sy, ay);
            az = fmaf(wap, sz, az); awc = fmaf(wap, sw, awc);
        }
    }
    *(ushort4*)(out + (size_t)row * D + ch) = make_ushort4(f2b(ax), f2b(ay), f2b(az), f2b(awc));
}

// ---------------------------------------------------------------------
// out = LayerNorm(a + b) * g + beta over D=256. Optional bf16 second out.
// Alias-safe: out may equal a or b (no __restrict__ on those).
// ---------------------------------------------------------------------
__global__ __launch_bounds__(256) void add_ln(const float* a,
                                              const float* b,
                                              const float* __restrict__ g,
                                              const float* __restrict__ be,
                                              float* out,
                                              unsigned short* outb)
{
    __shared__ float red[256];
    const int row = blockIdx.x, t = threadIdx.x;
    const size_t base = (size_t)row * D;
    const float v = a[base + t] + b[base + t];
    red[t] = v; __syncthreads();
    for (int s = 128; s > 0; s >>= 1) { if (t < s) red[t] += red[t + s]; __syncthreads(); }
    const float mean = red[0] * (1.f / D);
    __syncthreads();
    const float dv = v - mean;
    red[t] = dv * dv; __syncthreads();
    for (int s = 128; s > 0; s >>= 1) { if (t < s) red[t] += red[t + s]; __syncthreads(); }
    const float var = red[0] * (1.f / D);
    const float o = dv * rsqrtf(var + 1e-5f) * g[t] + be[t];
    out[base + t] = o;
    if (outb) outb[base + t] = f2b(o);
}

// ---------------------------------------------------------------------
__global__ __launch_bounds__(256) void text_kv(const float* __restrict__ text,
                                               const float* __restrict__ ipw,
                                               const float* __restrict__ ipb,
                                               float* __restrict__ kh,
                                               float* __restrict__ vh)
{
    __shared__ float ts[D];
    const int row = blockIdx.x, t = threadIdx.x;
    ts[t] = text[(size_t)row * D + t];
    __syncthreads();
    const float* wk = ipw + (size_t)(D + t) * D;
    const float* wv = ipw + (size_t)(2 * D + t) * D;
    float sk = ipb[D + t], sv = ipb[2 * D + t];
    for (int k = 0; k < D; ++k) {
        sk = fmaf(ts[k], wk[k], sk);
        sv = fmaf(ts[k], wv[k], sv);
    }
    kh[(size_t)row * D + t] = sk;
    vh[(size_t)row * D + t] = sv;
}

// ---------------------------------------------------------------------
// cross-attention to text; ctx written as bf16
// ---------------------------------------------------------------------
__global__ __launch_bounds__(256) void text_attn(const float* __restrict__ qh,
                                                 const float* __restrict__ kh,
                                                 const float* __restrict__ vh,
                                                 unsigned short* __restrict__ ctx)
{
    __shared__ float qs[D];
    __shared__ float sc[NH][LT];
    const int row = blockIdx.x, t = threadIdx.x;
    const int b = row / LQ;
    const int h = t >> 5, d = t & 31;
    qs[t] = qh[(size_t)row * D + t];
    __syncthreads();
    if (d < LT) {
        const float* kr = kh + (size_t)(b * LT + d) * D + h * HDIM;
        float s = 0.f;
#pragma unroll
        for (int dd = 0; dd < HDIM; ++dd) s = fmaf(qs[h * HDIM + dd], kr[dd], s);
        sc[h][d] = s * 0.17677669529663687f;
    }
    __syncthreads();
    float m = -1e30f;
#pragma unroll
    for (int k = 0; k < LT; ++k) m = fmaxf(m, sc[h][k]);
    float sum = 0.f;
#pragma unroll
    for (int k = 0; k < LT; ++k) sum += __expf(sc[h][k] - m);
    const float inv = 1.f / sum;
    float o = 0.f;
#pragma unroll
    for (int k = 0; k < LT; ++k)
        o = fmaf(__expf(sc[h][k] - m) * inv, vh[(size_t)(b * LT + k) * D + h * HDIM + d], o);
    ctx[(size_t)row * D + t] = f2b(o);
}

// ---------------------------------------------------------------------
__global__ __launch_bounds__(256) void copy_text(const float* __restrict__ text,
                                                 float* __restrict__ out)
{
    const int i = blockIdx.x * 256 + threadIdx.x;
    out[i] = text[i];
}

// =====================================================================
extern "C" void kernel_launch(void* const* d_in, const int* in_sizes, int n_in,
                              void* d_out, int out_size, void* d_ws, size_t ws_size,
                              hipStream_t stream)
{
    const float* src  = (const float*)d_in[0];
    const float* pos  = (const float*)d_in[1];
    const float* refp = (const float*)d_in[2];
    const float* text = (const float*)d_in[5];
    const float* so_w = (const float*)d_in[7];
    const float* so_b = (const float*)d_in[8];
    const float* aw_w = (const float*)d_in[9];
    const float* aw_b = (const float*)d_in[10];
    const float* vp_w = (const float*)d_in[11];
    const float* vp_b = (const float*)d_in[12];
    const float* op_w = (const float*)d_in[13];
    const float* op_b = (const float*)d_in[14];
    const float* ln1g = (const float*)d_in[15];
    const float* ln1b = (const float*)d_in[16];
    const float* ipw  = (const float*)d_in[17];
    const float* ipb  = (const float*)d_in[18];
    const float* mow  = (const float*)d_in[19];
    const float* mob  = (const float*)d_in[20];
    const float* ln3g = (const float*)d_in[21];
    const float* ln3b = (const float*)d_in[22];
    const float* l1w  = (const float*)d_in[23];
    const float* l1b  = (const float*)d_in[24];
    const float* l2w  = (const float*)d_in[25];
    const float* l2b  = (const float*)d_in[26];
    const float* ln2g = (const float*)d_in[27];
    const float* ln2b = (const float*)d_in[28];

    float* ws = (float*)d_ws;
    // float-unit slot layout (total 5.5*SFL floats, same budget as round 1/2):
    // [0.0,1.0) offs fp32            | later: hidden_bf (with S1,S2)
    // [1.0,1.5) awl fp32             |
    // [1.5,2.0) src_bf -> mscore_bf  |
    // [2.0,2.5) q_bf -> q2_bf -> ctx_bf -> x2_bf
    // [2.5,3.0) value_bf
    // [3.0,4.0) ms / qh / mha fp32
    // [4.0,5.0) x1 fp32 -> x2 fp32 (in-place)
    // [5.0,5.5) weight bf16 arena + text K/V fp32
    float*          offs   = ws;
    float*          awl    = ws + SFL;
    unsigned short* srcb   = (unsigned short*)(ws + SFL + SFL / 2);
    unsigned short* mscb   = srcb;
    unsigned short* qbf    = (unsigned short*)(ws + 2 * SFL);
    unsigned short* valb   = (unsigned short*)(ws + 2 * SFL + SFL / 2);
    float*          gen32  = ws + 3 * SFL;          // ms/qh/mha
    float*          x12    = ws + 4 * SFL;          // x1 then x2 in-place
    unsigned short* wb     = (unsigned short*)(ws + 5 * SFL);
    unsigned short* hidden = (unsigned short*)ws;   // [0,2.0) : N x 1024 bf16

    // weight arena offsets (bf16 elements)
    unsigned short* wb_vp = wb;
    unsigned short* wb_so = wb + 65536;
    unsigned short* wb_aw = wb + 131072;
    unsigned short* wb_op = wb + 163840;
    unsigned short* wb_wq = wb + 229376;
    unsigned short* wb_mo = wb + 294912;
    unsigned short* wb_l1 = wb + 360448;
    unsigned short* wb_l2 = wb + 622592;            // end 884736 bf16 = 442368 floats
    float* kvk = ws + 5 * SFL + 442368;
    float* kvv = kvk + (size_t)BB * LT * D;

    const int M = NROWS;
    const int gx = (M + 127) / 128;                 // 316
    const dim3 blk(256);
    const int n4 = (int)(SFL / 4);
    const int vgrid = (n4 + 255) / 256;
    const int dgrid = (M + 3) / 4;

    // 0. weight casts (one launch, 8 segments)
    W8 w8;
    w8.s[0] = vp_w; w8.d[0] = wb_vp; w8.n[0] = 65536;
    w8.s[1] = so_w; w8.d[1] = wb_so; w8.n[1] = 65536;
    w8.s[2] = aw_w; w8.d[2] = wb_aw; w8.n[2] = 32768;
    w8.s[3] = op_w; w8.d[3] = wb_op; w8.n[3] = 65536;
    w8.s[4] = ipw;  w8.d[4] = wb_wq; w8.n[4] = 65536;   // wq = first 256 rows
    w8.s[5] = mow;  w8.d[5] = wb_mo; w8.n[5] = 65536;
    w8.s[6] = l1w;  w8.d[6] = wb_l1; w8.n[6] = 262144;
    w8.s[7] = l2w;  w8.d[7] = wb_l2; w8.n[7] = 262144;
    cast_w8<<<dim3(128, 8), blk, 0, stream>>>(w8);
    // 0b. src -> bf16
    cast4<<<dim3(vgrid), blk, 0, stream>>>((const float4*)src, (ushort4*)srcb, n4);
    // 1. q = src + pos -> bf16
    add2_bf<<<dim3(vgrid), blk, 0, stream>>>((const float4*)src, (const float4*)pos, (ushort4*)qbf, n4);
    // 2. value = src @ vp^T + b -> bf16
    gemm_mfma<<<dim3(gx, 2), blk, 0, stream>>>(srcb, wb_vp, vp_b, nullptr, valb, M, 256, 256, 0);
    // 3. offs = q @ so^T + b -> fp32
    gemm_mfma<<<dim3(gx, 2), blk, 0, stream>>>(qbf, wb_so, so_b, offs, nullptr, M, 256, 256, 0);
    // 4. aw logits = q @ aw^T + b -> fp32
    gemm_mfma<<<dim3(gx, 1), blk, 0, stream>>>(qbf, wb_aw, aw_b, awl, nullptr, M, 128, 256, 0);
    // 5. softmax
    softmax16<<<dim3((M * NH + 255) / 256), blk, 0, stream>>>(awl, M * NH);
    // 6. deformable sampling -> mscore bf16
    msdeform<<<dim3(dgrid), blk, 0, stream>>>(valb, offs, awl, refp, mscb);
    // 7. ms = mscore @ op^T + b -> fp32
    gemm_mfma<<<dim3(gx, 2), blk, 0, stream>>>(mscb, wb_op, op_b, gen32, nullptr, M, 256, 256, 0);
    // 8. x1 = LN(src + ms) -> x12 (fp32)
    add_ln<<<dim3(M), blk, 0, stream>>>(src, gen32, ln1g, ln1b, x12, nullptr);
    // 9. q2 = x1 + pos -> bf16
    add2_bf<<<dim3(vgrid), blk, 0, stream>>>((const float4*)x12, (const float4*)pos, (ushort4*)qbf, n4);
    // 10. text K/V (fp32)
    text_kv<<<dim3(BB * LT), blk, 0, stream>>>(text, ipw, ipb, kvk, kvv);
    // 11. qh = q2 @ wq^T + bq -> fp32
    gemm_mfma<<<dim3(gx, 2), blk, 0, stream>>>(qbf, wb_wq, ipb, gen32, nullptr, M, 256, 256, 0);
    // 12. ctx = attn(qh, K, V) -> bf16
    text_attn<<<dim3(M), blk, 0, stream>>>(gen32, kvk, kvv, qbf);
    // 13. mha = ctx @ mow^T + b -> fp32
    gemm_mfma<<<dim3(gx, 2), blk, 0, stream>>>(qbf, wb_mo, mob, gen32, nullptr, M, 256, 256, 0);
    // 14. x2 = LN(x1 + mha) -> x12 in-place (fp32) + bf16 copy
    add_ln<<<dim3(M), blk, 0, stream>>>(x12, gen32, ln3g, ln3b, x12, qbf);
    // 15. hidden = relu(x2 @ l1^T + b) -> bf16
    gemm_mfma<<<dim3(gx, 8), blk, 0, stream>>>(qbf, wb_l1, l1b, nullptr, hidden, M, 1024, 256, 1);
    // 16. ffn = hidden @ l2^T + b -> d_out (fp32 scratch)
    float* outx = (float*)d_out;
    gemm_mfma<<<dim3(gx, 2), blk, 0, stream>>>(hidden, wb_l2, l2b, outx, nullptr, M, 256, 1024, 0);
    // 17. x3 = LN(x2 + ffn) -> d_out
    add_ln<<<dim3(M), blk, 0, stream>>>(x12, outx, ln2g, ln2b, outx, nullptr);
    // 18. text passthrough
    copy_text<<<dim3(BB * LT), blk, 0, stream>>>(text, outx + SFL);
}

// Round 4
// 759.169 us; speedup vs baseline: 2.6127x; 1.3237x over previous
//
#include <hip/hip_runtime.h>
#include <math.h>

// ---------------- problem constants ----------------
#define D     256
#define NH    8
#define HDIM  32
#define NL    4
#define NPT   4
#define DFF   1024
#define BB    2
#define LT    20
#define LQ    20197
#define NROWS (BB*LQ)                 // 40394
#define SFL   ((size_t)NROWS * D)     // floats per N x 256 buffer

typedef __attribute__((ext_vector_type(8))) short bf16x8;
typedef __attribute__((ext_vector_type(4))) float f32x4;

__device__ __forceinline__ unsigned short f2b(float f) {
    unsigned int u = __float_as_uint(f);
    unsigned int r = (u + 0x7FFFu + ((u >> 16) & 1u)) >> 16;   // RNE
    return (unsigned short)r;
}
__device__ __forceinline__ float b2f(unsigned short u) {
    return __uint_as_float((unsigned int)u << 16);
}
__device__ __forceinline__ unsigned int pk2(float a, float b) {
    return (unsigned int)f2b(a) | ((unsigned int)f2b(b) << 16);
}

#define GLDS16(g, l) __builtin_amdgcn_global_load_lds( \
    (const __attribute__((address_space(1))) unsigned int*)(g), \
    (__attribute__((address_space(3))) unsigned int*)(l), 16, 0, 0)

// =====================================================================
// bf16 MFMA GEMM:  C[M,Nout] = A[M,K](bf16) @ W[Nout,K](bf16)^T + bias
// 128x128 tile, BK=32, 4 waves (2x2 of 64x64), mfma_f32_16x16x32_bf16.
// Output fp32 (Cf) or bf16 (Cb, with optional relu). Nout%128==0, K%32==0.
// =====================================================================
__global__ __launch_bounds__(256) void gemm_mfma(const unsigned short* __restrict__ A,
                                                 const unsigned short* __restrict__ W,
                                                 const float* __restrict__ bias,
                                                 float* __restrict__ Cf,
                                                 unsigned short* __restrict__ Cb,
                                                 int M, int Nout, int K, int relu)
{
    __shared__ __align__(16) unsigned short As[128 * 32];
    __shared__ __align__(16) unsigned short Ws[128 * 32];
    const int tid  = threadIdx.x;
    const int wave = tid >> 6, lane = tid & 63;
    const int row0 = blockIdx.x * 128, n0 = blockIdx.y * 128;
    const int wm = (wave >> 1) * 64, wn = (wave & 1) * 64;

    const int srow = (wave << 5) + (lane >> 2);
    const int kcol = (lane & 3) << 3;
    const int ar0 = min(row0 + srow,      M - 1);
    const int ar1 = min(row0 + srow + 16, M - 1);
    const unsigned short* Ap0 = A + (size_t)ar0 * K + kcol;
    const unsigned short* Ap1 = A + (size_t)ar1 * K + kcol;
    const unsigned short* Wp0 = W + (size_t)(n0 + srow) * K + kcol;
    const unsigned short* Wp1 = W + (size_t)(n0 + srow + 16) * K + kcol;
    unsigned short* lA0 = &As[(wave << 10)];
    unsigned short* lA1 = &As[(wave << 10) + 512];
    unsigned short* lW0 = &Ws[(wave << 10)];
    unsigned short* lW1 = &Ws[(wave << 10) + 512];

    f32x4 acc[4][4];
#pragma unroll
    for (int i = 0; i < 4; ++i)
#pragma unroll
        for (int j = 0; j < 4; ++j)
#pragma unroll
            for (int r = 0; r < 4; ++r) acc[i][j][r] = 0.f;

    const int fr = lane & 15;
    const int fk = (lane >> 4) << 3;

    for (int k0 = 0; k0 < K; k0 += 32) {
        GLDS16(Ap0 + k0, lA0);
        GLDS16(Ap1 + k0, lA1);
        GLDS16(Wp0 + k0, lW0);
        GLDS16(Wp1 + k0, lW1);
        __syncthreads();
        bf16x8 af[4], wf[4];
#pragma unroll
        for (int t = 0; t < 4; ++t) {
            af[t] = *(const bf16x8*)&As[(wm + t * 16 + fr) * 32 + fk];
            wf[t] = *(const bf16x8*)&Ws[(wn + t * 16 + fr) * 32 + fk];
        }
#pragma unroll
        for (int i = 0; i < 4; ++i)
#pragma unroll
            for (int j = 0; j < 4; ++j)
                acc[i][j] = __builtin_amdgcn_mfma_f32_16x16x32_bf16(af[i], wf[j], acc[i][j], 0, 0, 0);
        __syncthreads();
    }

    const int rq = (lane >> 4) << 2;
    const int cq = lane & 15;
#pragma unroll
    for (int mt = 0; mt < 4; ++mt) {
#pragma unroll
        for (int r = 0; r < 4; ++r) {
            const int row = row0 + wm + mt * 16 + rq + r;
            if (row < M) {
#pragma unroll
                for (int nt = 0; nt < 4; ++nt) {
                    const int c = n0 + wn + nt * 16 + cq;
                    float v = acc[mt][nt][r] + bias[c];
                    if (relu) v = fmaxf(v, 0.f);
                    if (Cb) Cb[(size_t)row * Nout + c] = f2b(v);
                    else    Cf[(size_t)row * Nout + c] = v;
                }
            }
        }
    }
}

// ---------------------------------------------------------------------
// batched fp32 -> bf16 weight cast (8 segments)
// ---------------------------------------------------------------------
struct W8 {
    const float* s[8];
    unsigned short* d[8];
    int n[8];
};
__global__ __launch_bounds__(256) void cast_w8(W8 w)
{
    const int seg = blockIdx.y;
    const int n = w.n[seg];
    const float* s = w.s[seg];
    unsigned short* d = w.d[seg];
    for (int i = blockIdx.x * 256 + threadIdx.x; i < n; i += gridDim.x * 256)
        d[i] = f2b(s[i]);
}

// concat so_b(256) + aw_b(128) -> o(384)
__global__ __launch_bounds__(384) void cat_bias(const float* __restrict__ sb,
                                                const float* __restrict__ ab,
                                                float* __restrict__ o)
{
    const int t = threadIdx.x;
    o[t] = (t < 256) ? sb[t] : ab[t - 256];
}

// srcb = bf16(src); qbf = bf16(src + pos)    (one pass)
__global__ __launch_bounds__(256) void cast_pair(const float4* __restrict__ src,
                                                 const float4* __restrict__ pos,
                                                 ushort4* __restrict__ srcb,
                                                 ushort4* __restrict__ qbf, int n4)
{
    const int i = blockIdx.x * 256 + threadIdx.x;
    if (i < n4) {
        const float4 s = src[i], p = pos[i];
        srcb[i] = make_ushort4(f2b(s.x), f2b(s.y), f2b(s.z), f2b(s.w));
        qbf[i]  = make_ushort4(f2b(s.x + p.x), f2b(s.y + p.y), f2b(s.z + p.z), f2b(s.w + p.w));
    }
}

// ---------------------------------------------------------------------
// multi-scale deformable sampling v4.
// 2 queries per wave; 4 lanes per head, each lane owns 8 channels (16B bf16).
// Softmax over the 16 attention logits fused in (group-of-4 shuffle).
// oa layout: N x 384 row-major: [0:256) sampling offsets, [256:384) logits.
// Branch-free corners: clamp index, zero weight, unconditional b128 gathers.
// ---------------------------------------------------------------------
__global__ __launch_bounds__(256) void msdeform(const unsigned short* __restrict__ value,
                                                const float* __restrict__ oa,
                                                const float* __restrict__ refp,
                                                unsigned short* __restrict__ out)
{
    const int Hs[4]  = {100, 50, 25, 13};
    const int Wsd[4] = {152, 76, 38, 19};
    const int St[4]  = {0, 15200, 19000, 19950};
    const int tid  = threadIdx.x;
    const int lane = tid & 63;
    const int row  = blockIdx.x * 8 + ((tid >> 6) << 1) + (lane >> 5);
    if (row >= NROWS) return;                 // 32-lane halves exit together
    const int b   = row / LQ;
    const int sub = lane & 31;
    const int h   = sub >> 2;                 // head 0..7
    const int j   = sub & 3;                  // 4 lanes per head
    const int ch  = (h << 5) + (j << 3);      // 8 channels per lane
    const unsigned short* vbase = value + (size_t)b * LQ * D + ch;

    const float* orow = oa + (size_t)row * 384;
    // offsets: lane j holds points 4j..4j+3 (x,y interleaved)
    const float4 o0 = *(const float4*)(orow + (h << 5) + (j << 3));
    const float4 o1 = *(const float4*)(orow + (h << 5) + (j << 3) + 4);
    const float oxr[4] = {o0.x, o0.z, o1.x, o1.z};
    const float oyr[4] = {o0.y, o0.w, o1.y, o1.w};
    // logits -> softmax over 16 (4 local + group-of-4 shuffle reduce)
    const float4 lg = *(const float4*)(orow + 256 + (h << 4) + (j << 2));
    float mx = fmaxf(fmaxf(lg.x, lg.y), fmaxf(lg.z, lg.w));
    mx = fmaxf(mx, __shfl_xor(mx, 1));
    mx = fmaxf(mx, __shfl_xor(mx, 2));
    const float e0 = __expf(lg.x - mx), e1 = __expf(lg.y - mx);
    const float e2 = __expf(lg.z - mx), e3 = __expf(lg.w - mx);
    float sm = e0 + e1 + e2 + e3;
    sm += __shfl_xor(sm, 1);
    sm += __shfl_xor(sm, 2);
    const float inv = 1.f / sm;
    const float pr[4] = {e0 * inv, e1 * inv, e2 * inv, e3 * inv};
    // reference points (all lanes of group load same rows -> broadcast)
    const float4 r01 = *(const float4*)(refp + (size_t)row * 8);
    const float4 r23 = *(const float4*)(refp + (size_t)row * 8 + 4);
    const float rxr[4] = {r01.x, r01.z, r23.x, r23.z};
    const float ryr[4] = {r01.y, r01.w, r23.y, r23.w};

    float acc[8] = {0.f,0.f,0.f,0.f,0.f,0.f,0.f,0.f};
    const int gb = lane & ~3;
#pragma unroll
    for (int t = 0; t < 16; ++t) {
        const int l = t >> 2;
        const int Wi = Wsd[l], Hi = Hs[l], s = St[l];
        const float Wf = (float)Wi, Hf = (float)Hi;
        const int srcl = gb + (t >> 2);
        const float ox  = __shfl(oxr[t & 3], srcl);
        const float oy  = __shfl(oyr[t & 3], srcl);
        const float wap = __shfl(pr[t & 3],  srcl);
        const float x = (rxr[l] + ox / Wf) * Wf - 0.5f;
        const float y = (ryr[l] + oy / Hf) * Hf - 0.5f;
        const float x0f = floorf(x), y0f = floorf(y);
        const float lx = x - x0f, ly = y - y0f;
        const int x0 = (int)x0f, y0 = (int)y0f;
        const int x1i = x0 + 1, y1i = y0 + 1;
        const float vx0 = (x0  >= 0 && x0  < Wi) ? 1.f : 0.f;
        const float vx1 = (x1i >= 0 && x1i < Wi) ? 1.f : 0.f;
        const float vy0 = (y0  >= 0 && y0  < Hi) ? 1.f : 0.f;
        const float vy1 = (y1i >= 0 && y1i < Hi) ? 1.f : 0.f;
        const int cx0 = min(max(x0, 0), Wi - 1), cx1 = min(max(x1i, 0), Wi - 1);
        const int cy0 = min(max(y0, 0), Hi - 1), cy1 = min(max(y1i, 0), Hi - 1);
        const float wc[4] = {(1.f-lx)*(1.f-ly)*vx0*vy0*wap, lx*(1.f-ly)*vx1*vy0*wap,
                             (1.f-lx)*ly*vx0*vy1*wap,       lx*ly*vx1*vy1*wap};
        const int idx[4] = {s + cy0*Wi + cx0, s + cy0*Wi + cx1,
                            s + cy1*Wi + cx0, s + cy1*Wi + cx1};
#pragma unroll
        for (int c = 0; c < 4; ++c) {
            const uint4 g = *(const uint4*)(vbase + (size_t)idx[c] * D);
            const float w = wc[c];
            acc[0] = fmaf(w, __uint_as_float(g.x << 16),          acc[0]);
            acc[1] = fmaf(w, __uint_as_float(g.x & 0xffff0000u),  acc[1]);
            acc[2] = fmaf(w, __uint_as_float(g.y << 16),          acc[2]);
            acc[3] = fmaf(w, __uint_as_float(g.y & 0xffff0000u),  acc[3]);
            acc[4] = fmaf(w, __uint_as_float(g.z << 16),          acc[4]);
            acc[5] = fmaf(w, __uint_as_float(g.z & 0xffff0000u),  acc[5]);
            acc[6] = fmaf(w, __uint_as_float(g.w << 16),          acc[6]);
            acc[7] = fmaf(w, __uint_as_float(g.w & 0xffff0000u),  acc[7]);
        }
    }
    uint4 o;
    o.x = pk2(acc[0], acc[1]); o.y = pk2(acc[2], acc[3]);
    o.z = pk2(acc[4], acc[5]); o.w = pk2(acc[6], acc[7]);
    *(uint4*)(out + (size_t)row * D + ch) = o;
}

// ---------------------------------------------------------------------
// out = LayerNorm(a + b) * g + beta over D=256. ONE WAVE per row (shuffle
// reduction, no barriers). Optional bf16 out; if pos != null, bf16 out is
// f2b(out + pos). Alias-safe (reads complete before writes per wave).
// ---------------------------------------------------------------------
__global__ __launch_bounds__(256) void add_ln(const float* a, const float* b,
                                              const float* __restrict__ g,
                                              const float* __restrict__ be,
                                              const float* __restrict__ pos,
                                              float* out, unsigned short* outb)
{
    const int lane = threadIdx.x & 63;
    const int row  = blockIdx.x * 4 + (threadIdx.x >> 6);
    if (row >= NROWS) return;
    const size_t base = (size_t)row * D + (lane << 2);
    const float4 av = *(const float4*)(a + base);
    const float4 bv = *(const float4*)(b + base);
    float4 v = make_float4(av.x + bv.x, av.y + bv.y, av.z + bv.z, av.w + bv.w);
    float s = v.x + v.y + v.z + v.w;
#pragma unroll
    for (int off = 1; off < 64; off <<= 1) s += __shfl_xor(s, off);
    const float mean = s * (1.f / 256.f);
    const float4 d = make_float4(v.x - mean, v.y - mean, v.z - mean, v.w - mean);
    float q = d.x*d.x + d.y*d.y + d.z*d.z + d.w*d.w;
#pragma unroll
    for (int off = 1; off < 64; off <<= 1) q += __shfl_xor(q, off);
    const float rstd = rsqrtf(q * (1.f / 256.f) + 1e-5f);
    const float4 gv = *(const float4*)(g  + (lane << 2));
    const float4 bev = *(const float4*)(be + (lane << 2));
    float4 o;
    o.x = d.x * rstd * gv.x + bev.x;
    o.y = d.y * rstd * gv.y + bev.y;
    o.z = d.z * rstd * gv.z + bev.z;
    o.w = d.w * rstd * gv.w + bev.w;
    *(float4*)(out + base) = o;
    if (outb) {
        float4 p = make_float4(0.f, 0.f, 0.f, 0.f);
        if (pos) p = *(const float4*)(pos + base);
        uint2 u;
        u.x = pk2(o.x + p.x, o.y + p.y);
        u.y = pk2(o.z + p.z, o.w + p.w);
        *(uint2*)(outb + base) = u;
    }
}

// ---------------------------------------------------------------------
__global__ __launch_bounds__(256) void text_kv(const float* __restrict__ text,
                                               const float* __restrict__ ipw,
                                               const float* __restrict__ ipb,
                                               float* __restrict__ kh,
                                               float* __restrict__ vh)
{
    __shared__ float ts[D];
    const int row = blockIdx.x, t = threadIdx.x;
    ts[t] = text[(size_t)row * D + t];
    __syncthreads();
    const float* wk = ipw + (size_t)(D + t) * D;
    const float* wv = ipw + (size_t)(2 * D + t) * D;
    float sk = ipb[D + t], sv = ipb[2 * D + t];
    for (int k = 0; k < D; ++k) {
        sk = fmaf(ts[k], wk[k], sk);
        sv = fmaf(ts[k], wv[k], sv);
    }
    kh[(size_t)row * D + t] = sk;
    vh[(size_t)row * D + t] = sv;
}

// ---------------------------------------------------------------------
// cross-attention to text; ctx written as bf16
// ---------------------------------------------------------------------
__global__ __launch_bounds__(256) void text_attn(const float* __restrict__ qh,
                                                 const float* __restrict__ kh,
                                                 const float* __restrict__ vh,
                                                 unsigned short* __restrict__ ctx)
{
    __shared__ float qs[D];
    __shared__ float sc[NH][LT];
    const int row = blockIdx.x, t = threadIdx.x;
    const int b = row / LQ;
    const int h = t >> 5, d = t & 31;
    qs[t] = qh[(size_t)row * D + t];
    __syncthreads();
    if (d < LT) {
        const float* kr = kh + (size_t)(b * LT + d) * D + h * HDIM;
        float s = 0.f;
#pragma unroll
        for (int dd = 0; dd < HDIM; ++dd) s = fmaf(qs[h * HDIM + dd], kr[dd], s);
        sc[h][d] = s * 0.17677669529663687f;
    }
    __syncthreads();
    float m = -1e30f;
#pragma unroll
    for (int k = 0; k < LT; ++k) m = fmaxf(m, sc[h][k]);
    float sum = 0.f;
#pragma unroll
    for (int k = 0; k < LT; ++k) sum += __expf(sc[h][k] - m);
    const float inv = 1.f / sum;
    float o = 0.f;
#pragma unroll
    for (int k = 0; k < LT; ++k)
        o = fmaf(__expf(sc[h][k] - m) * inv, vh[(size_t)(b * LT + k) * D + h * HDIM + d], o);
    ctx[(size_t)row * D + t] = f2b(o);
}

// ---------------------------------------------------------------------
__global__ __launch_bounds__(256) void copy_text(const float* __restrict__ text,
                                                 float* __restrict__ out)
{
    const int i = blockIdx.x * 256 + threadIdx.x;
    out[i] = text[i];
}

// =====================================================================
extern "C" void kernel_launch(void* const* d_in, const int* in_sizes, int n_in,
                              void* d_out, int out_size, void* d_ws, size_t ws_size,
                              hipStream_t stream)
{
    const float* src  = (const float*)d_in[0];
    const float* pos  = (const float*)d_in[1];
    const float* refp = (const float*)d_in[2];
    const float* text = (const float*)d_in[5];
    const float* so_w = (const float*)d_in[7];
    const float* so_b = (const float*)d_in[8];
    const float* aw_w = (const float*)d_in[9];
    const float* aw_b = (const float*)d_in[10];
    const float* vp_w = (const float*)d_in[11];
    const float* vp_b = (const float*)d_in[12];
    const float* op_w = (const float*)d_in[13];
    const float* op_b = (const float*)d_in[14];
    const float* ln1g = (const float*)d_in[15];
    const float* ln1b = (const float*)d_in[16];
    const float* ipw  = (const float*)d_in[17];
    const float* ipb  = (const float*)d_in[18];
    const float* mow  = (const float*)d_in[19];
    const float* mob  = (const float*)d_in[20];
    const float* ln3g = (const float*)d_in[21];
    const float* ln3b = (const float*)d_in[22];
    const float* l1w  = (const float*)d_in[23];
    const float* l1b  = (const float*)d_in[24];
    const float* l2w  = (const float*)d_in[25];
    const float* l2b  = (const float*)d_in[26];
    const float* ln2g = (const float*)d_in[27];
    const float* ln2b = (const float*)d_in[28];

    float* ws = (float*)d_ws;
    // slot layout (float units):
    // [0.0,1.5) oa fp32 (N x 384: offs | logits)   -> later hidden bf16 [0,2.0)
    // [1.5,2.0) srcb bf16 -> mscb bf16
    // [2.0,2.5) qbf bf16 (q -> q2 -> ctx -> x2)
    // [2.5,3.0) valb bf16
    // [3.0,4.0) gen32 fp32 (ms / qh / mha)
    // [4.0,5.0) x12 fp32 (x1 -> x2, in-place)
    // [5.0,5.5) weight bf16 arena + kv + cat bias
    float*          oa     = ws;
    unsigned short* srcb   = (unsigned short*)(ws + SFL + SFL / 2);
    unsigned short* mscb   = srcb;
    unsigned short* qbf    = (unsigned short*)(ws + 2 * SFL);
    unsigned short* valb   = (unsigned short*)(ws + 2 * SFL + SFL / 2);
    float*          gen32  = ws + 3 * SFL;
    float*          x12    = ws + 4 * SFL;
    unsigned short* wb     = (unsigned short*)(ws + 5 * SFL);
    unsigned short* hidden = (unsigned short*)ws;   // N x 1024 bf16 overlays [0,2.0)

    unsigned short* wb_vp = wb;
    unsigned short* wb_so = wb + 65536;             // so(256 rows) then aw(128 rows) contiguous
    unsigned short* wb_aw = wb + 131072;
    unsigned short* wb_op = wb + 163840;
    unsigned short* wb_wq = wb + 229376;
    unsigned short* wb_mo = wb + 294912;
    unsigned short* wb_l1 = wb + 360448;
    unsigned short* wb_l2 = wb + 622592;            // end 884736 shorts = 442368 floats
    float* kvk  = ws + 5 * SFL + 442368;
    float* kvv  = kvk + (size_t)BB * LT * D;
    float* sobc = kvv + (size_t)BB * LT * D;        // 384 floats

    const int M = NROWS;
    const int gx = (M + 127) / 128;                 // 316
    const dim3 blk(256);
    const int n4 = (int)(SFL / 4);
    const int vgrid = (n4 + 255) / 256;
    const int dgrid = (M + 7) / 8;                  // msdeform: 8 queries/block
    const int lgrid = (M + 3) / 4;                  // add_ln: 4 rows/block

    // 0. weight casts
    W8 w8;
    w8.s[0] = vp_w; w8.d[0] = wb_vp; w8.n[0] = 65536;
    w8.s[1] = so_w; w8.d[1] = wb_so; w8.n[1] = 65536;
    w8.s[2] = aw_w; w8.d[2] = wb_aw; w8.n[2] = 32768;
    w8.s[3] = op_w; w8.d[3] = wb_op; w8.n[3] = 65536;
    w8.s[4] = ipw;  w8.d[4] = wb_wq; w8.n[4] = 65536;
    w8.s[5] = mow;  w8.d[5] = wb_mo; w8.n[5] = 65536;
    w8.s[6] = l1w;  w8.d[6] = wb_l1; w8.n[6] = 262144;
    w8.s[7] = l2w;  w8.d[7] = wb_l2; w8.n[7] = 262144;
    cast_w8<<<dim3(128, 8), blk, 0, stream>>>(w8);
    cat_bias<<<dim3(1), dim3(384), 0, stream>>>(so_b, aw_b, sobc);
    // 1. srcb = bf16(src), qbf = bf16(src+pos)
    cast_pair<<<dim3(vgrid), blk, 0, stream>>>((const float4*)src, (const float4*)pos,
                                               (ushort4*)srcb, (ushort4*)qbf, n4);
    // 2. value = src @ vp^T + b -> bf16
    gemm_mfma<<<dim3(gx, 2), blk, 0, stream>>>(srcb, wb_vp, vp_b, nullptr, valb, M, 256, 256, 0);
    // 3. merged offs+logits = q @ [so;aw]^T + b -> oa fp32 (N x 384)
    gemm_mfma<<<dim3(gx, 3), blk, 0, stream>>>(qbf, wb_so, sobc, oa, nullptr, M, 384, 256, 0);
    // 4. deformable sampling (softmax fused) -> mscore bf16
    msdeform<<<dim3(dgrid), blk, 0, stream>>>(valb, oa, refp, mscb);
    // 5. ms = mscore @ op^T + b -> fp32
    gemm_mfma<<<dim3(gx, 2), blk, 0, stream>>>(mscb, wb_op, op_b, gen32, nullptr, M, 256, 256, 0);
    // 6. x1 = LN(src + ms) -> x12; q2 = bf16(x1 + pos) -> qbf (fused)
    add_ln<<<dim3(lgrid), blk, 0, stream>>>(src, gen32, ln1g, ln1b, pos, x12, qbf);
    // 7. text K/V
    text_kv<<<dim3(BB * LT), blk, 0, stream>>>(text, ipw, ipb, kvk, kvv);
    // 8. qh = q2 @ wq^T + bq -> fp32
    gemm_mfma<<<dim3(gx, 2), blk, 0, stream>>>(qbf, wb_wq, ipb, gen32, nullptr, M, 256, 256, 0);
    // 9. ctx = attn(qh, K, V) -> bf16 (qbf reused)
    text_attn<<<dim3(M), blk, 0, stream>>>(gen32, kvk, kvv, qbf);
    // 10. mha = ctx @ mow^T + b -> fp32
    gemm_mfma<<<dim3(gx, 2), blk, 0, stream>>>(qbf, wb_mo, mob, gen32, nullptr, M, 256, 256, 0);
    // 11. x2 = LN(x1 + mha) -> x12 in-place; bf16 copy -> qbf
    add_ln<<<dim3(lgrid), blk, 0, stream>>>(x12, gen32, ln3g, ln3b, nullptr, x12, qbf);
    // 12. hidden = relu(x2 @ l1^T + b) -> bf16
    gemm_mfma<<<dim3(gx, 8), blk, 0, stream>>>(qbf, wb_l1, l1b, nullptr, hidden, M, 1024, 256, 1);
    // 13. ffn = hidden @ l2^T + b -> d_out (fp32 scratch)
    float* outx = (float*)d_out;
    gemm_mfma<<<dim3(gx, 2), blk, 0, stream>>>(hidden, wb_l2, l2b, outx, nullptr, M, 256, 1024, 0);
    // 14. x3 = LN(x2 + ffn) -> d_out
    add_ln<<<dim3(lgrid), blk, 0, stream>>>(x12, outx, ln2g, ln2b, nullptr, outx, nullptr);
    // 15. text passthrough
    copy_text<<<dim3(BB * LT), blk, 0, stream>>>(text, outx + SFL);
}

// Round 5
// 756.529 us; speedup vs baseline: 2.6218x; 1.0035x over previous
//
#include <hip/hip_runtime.h>
#include <math.h>

// ---------------- problem constants ----------------
#define D     256
#define NH    8
#define HDIM  32
#define NL    4
#define NPT   4
#define DFF   1024
#define BB    2
#define LT    20
#define LQ    20197
#define NROWS (BB*LQ)                 // 40394
#define SFL   ((size_t)NROWS * D)     // floats per N x 256 buffer

typedef __attribute__((ext_vector_type(8))) short bf16x8;
typedef __attribute__((ext_vector_type(4))) float f32x4;

__device__ __forceinline__ unsigned short f2b(float f) {
    unsigned int u = __float_as_uint(f);
    unsigned int r = (u + 0x7FFFu + ((u >> 16) & 1u)) >> 16;   // RNE
    return (unsigned short)r;
}
__device__ __forceinline__ float b2f(unsigned short u) {
    return __uint_as_float((unsigned int)u << 16);
}
__device__ __forceinline__ unsigned int pk2(float a, float b) {
    return (unsigned int)f2b(a) | ((unsigned int)f2b(b) << 16);
}

#define GLDS16(g, l) __builtin_amdgcn_global_load_lds( \
    (const __attribute__((address_space(1))) unsigned int*)(g), \
    (__attribute__((address_space(3))) unsigned int*)(l), 16, 0, 0)

// =====================================================================
// bf16 MFMA GEMM:  C[M,Nout] = A[M,K](bf16) @ W[Nout,K](bf16)^T + bias
// 128x128 tile, BK=32, 4 waves (2x2 of 64x64), mfma_f32_16x16x32_bf16.
// Output fp32 (Cf) or bf16 (Cb, with optional relu). Nout%128==0, K%32==0.
// =====================================================================
__global__ __launch_bounds__(256) void gemm_mfma(const unsigned short* __restrict__ A,
                                                 const unsigned short* __restrict__ W,
                                                 const float* __restrict__ bias,
                                                 float* __restrict__ Cf,
                                                 unsigned short* __restrict__ Cb,
                                                 int M, int Nout, int K, int relu)
{
    __shared__ __align__(16) unsigned short As[128 * 32];
    __shared__ __align__(16) unsigned short Ws[128 * 32];
    const int tid  = threadIdx.x;
    const int wave = tid >> 6, lane = tid & 63;
    const int row0 = blockIdx.x * 128, n0 = blockIdx.y * 128;
    const int wm = (wave >> 1) * 64, wn = (wave & 1) * 64;

    const int srow = (wave << 5) + (lane >> 2);
    const int kcol = (lane & 3) << 3;
    const int ar0 = min(row0 + srow,      M - 1);
    const int ar1 = min(row0 + srow + 16, M - 1);
    const unsigned short* Ap0 = A + (size_t)ar0 * K + kcol;
    const unsigned short* Ap1 = A + (size_t)ar1 * K + kcol;
    const unsigned short* Wp0 = W + (size_t)(n0 + srow) * K + kcol;
    const unsigned short* Wp1 = W + (size_t)(n0 + srow + 16) * K + kcol;
    unsigned short* lA0 = &As[(wave << 10)];
    unsigned short* lA1 = &As[(wave << 10) + 512];
    unsigned short* lW0 = &Ws[(wave << 10)];
    unsigned short* lW1 = &Ws[(wave << 10) + 512];

    f32x4 acc[4][4];
#pragma unroll
    for (int i = 0; i < 4; ++i)
#pragma unroll
        for (int j = 0; j < 4; ++j)
#pragma unroll
            for (int r = 0; r < 4; ++r) acc[i][j][r] = 0.f;

    const int fr = lane & 15;
    const int fk = (lane >> 4) << 3;

    for (int k0 = 0; k0 < K; k0 += 32) {
        GLDS16(Ap0 + k0, lA0);
        GLDS16(Ap1 + k0, lA1);
        GLDS16(Wp0 + k0, lW0);
        GLDS16(Wp1 + k0, lW1);
        __syncthreads();
        bf16x8 af[4], wf[4];
#pragma unroll
        for (int t = 0; t < 4; ++t) {
            af[t] = *(const bf16x8*)&As[(wm + t * 16 + fr) * 32 + fk];
            wf[t] = *(const bf16x8*)&Ws[(wn + t * 16 + fr) * 32 + fk];
        }
#pragma unroll
        for (int i = 0; i < 4; ++i)
#pragma unroll
            for (int j = 0; j < 4; ++j)
                acc[i][j] = __builtin_amdgcn_mfma_f32_16x16x32_bf16(af[i], wf[j], acc[i][j], 0, 0, 0);
        __syncthreads();
    }

    const int rq = (lane >> 4) << 2;
    const int cq = lane & 15;
#pragma unroll
    for (int mt = 0; mt < 4; ++mt) {
#pragma unroll
        for (int r = 0; r < 4; ++r) {
            const int row = row0 + wm + mt * 16 + rq + r;
            if (row < M) {
#pragma unroll
                for (int nt = 0; nt < 4; ++nt) {
                    const int c = n0 + wn + nt * 16 + cq;
                    float v = acc[mt][nt][r] + bias[c];
                    if (relu) v = fmaxf(v, 0.f);
                    if (Cb) Cb[(size_t)row * Nout + c] = f2b(v);
                    else    Cf[(size_t)row * Nout + c] = v;
                }
            }
        }
    }
}

// ---------------------------------------------------------------------
// batched fp32 -> bf16 weight cast (8 segments)
// ---------------------------------------------------------------------
struct W8 {
    const float* s[8];
    unsigned short* d[8];
    int n[8];
};
__global__ __launch_bounds__(256) void cast_w8(W8 w)
{
    const int seg = blockIdx.y;
    const int n = w.n[seg];
    const float* s = w.s[seg];
    unsigned short* d = w.d[seg];
    for (int i = blockIdx.x * 256 + threadIdx.x; i < n; i += gridDim.x * 256)
        d[i] = f2b(s[i]);
}

// concat so_b(256) + aw_b(128) -> o(384)
__global__ __launch_bounds__(384) void cat_bias(const float* __restrict__ sb,
                                                const float* __restrict__ ab,
                                                float* __restrict__ o)
{
    const int t = threadIdx.x;
    o[t] = (t < 256) ? sb[t] : ab[t - 256];
}

// srcb = bf16(src); qbf = bf16(src + pos)    (one pass)
__global__ __launch_bounds__(256) void cast_pair(const float4* __restrict__ src,
                                                 const float4* __restrict__ pos,
                                                 ushort4* __restrict__ srcb,
                                                 ushort4* __restrict__ qbf, int n4)
{
    const int i = blockIdx.x * 256 + threadIdx.x;
    if (i < n4) {
        const float4 s = src[i], p = pos[i];
        srcb[i] = make_ushort4(f2b(s.x), f2b(s.y), f2b(s.z), f2b(s.w));
        qbf[i]  = make_ushort4(f2b(s.x + p.x), f2b(s.y + p.y), f2b(s.z + p.z), f2b(s.w + p.w));
    }
}

// ---------------------------------------------------------------------
// multi-scale deformable sampling v4.
// 2 queries per wave; 4 lanes per head, each lane owns 8 channels (16B bf16).
// Softmax over the 16 attention logits fused in (group-of-4 shuffle).
// oa layout: N x 384 row-major: [0:256) sampling offsets, [256:384) logits.
// ---------------------------------------------------------------------
__global__ __launch_bounds__(256) void msdeform(const unsigned short* __restrict__ value,
                                                const float* __restrict__ oa,
                                                const float* __restrict__ refp,
                                                unsigned short* __restrict__ out)
{
    const int Hs[4]  = {100, 50, 25, 13};
    const int Wsd[4] = {152, 76, 38, 19};
    const int St[4]  = {0, 15200, 19000, 19950};
    const int tid  = threadIdx.x;
    const int lane = tid & 63;
    const int row  = blockIdx.x * 8 + ((tid >> 6) << 1) + (lane >> 5);
    if (row >= NROWS) return;
    const int b   = row / LQ;
    const int sub = lane & 31;
    const int h   = sub >> 2;
    const int j   = sub & 3;
    const int ch  = (h << 5) + (j << 3);
    const unsigned short* vbase = value + (size_t)b * LQ * D + ch;

    const float* orow = oa + (size_t)row * 384;
    const float4 o0 = *(const float4*)(orow + (h << 5) + (j << 3));
    const float4 o1 = *(const float4*)(orow + (h << 5) + (j << 3) + 4);
    const float oxr[4] = {o0.x, o0.z, o1.x, o1.z};
    const float oyr[4] = {o0.y, o0.w, o1.y, o1.w};
    const float4 lg = *(const float4*)(orow + 256 + (h << 4) + (j << 2));
    float mx = fmaxf(fmaxf(lg.x, lg.y), fmaxf(lg.z, lg.w));
    mx = fmaxf(mx, __shfl_xor(mx, 1));
    mx = fmaxf(mx, __shfl_xor(mx, 2));
    const float e0 = __expf(lg.x - mx), e1 = __expf(lg.y - mx);
    const float e2 = __expf(lg.z - mx), e3 = __expf(lg.w - mx);
    float sm = e0 + e1 + e2 + e3;
    sm += __shfl_xor(sm, 1);
    sm += __shfl_xor(sm, 2);
    const float inv = 1.f / sm;
    const float pr[4] = {e0 * inv, e1 * inv, e2 * inv, e3 * inv};
    const float4 r01 = *(const float4*)(refp + (size_t)row * 8);
    const float4 r23 = *(const float4*)(refp + (size_t)row * 8 + 4);
    const float rxr[4] = {r01.x, r01.z, r23.x, r23.z};
    const float ryr[4] = {r01.y, r01.w, r23.y, r23.w};

    float acc[8] = {0.f,0.f,0.f,0.f,0.f,0.f,0.f,0.f};
    const int gb = lane & ~3;
#pragma unroll
    for (int t = 0; t < 16; ++t) {
        const int l = t >> 2;
        const int Wi = Wsd[l], Hi = Hs[l], s = St[l];
        const float Wf = (float)Wi, Hf = (float)Hi;
        const int srcl = gb + (t >> 2);
        const float ox  = __shfl(oxr[t & 3], srcl);
        const float oy  = __shfl(oyr[t & 3], srcl);
        const float wap = __shfl(pr[t & 3],  srcl);
        const float x = (rxr[l] + ox / Wf) * Wf - 0.5f;
        const float y = (ryr[l] + oy / Hf) * Hf - 0.5f;
        const float x0f = floorf(x), y0f = floorf(y);
        const float lx = x - x0f, ly = y - y0f;
        const int x0 = (int)x0f, y0 = (int)y0f;
        const int x1i = x0 + 1, y1i = y0 + 1;
        const float vx0 = (x0  >= 0 && x0  < Wi) ? 1.f : 0.f;
        const float vx1 = (x1i >= 0 && x1i < Wi) ? 1.f : 0.f;
        const float vy0 = (y0  >= 0 && y0  < Hi) ? 1.f : 0.f;
        const float vy1 = (y1i >= 0 && y1i < Hi) ? 1.f : 0.f;
        const int cx0 = min(max(x0, 0), Wi - 1), cx1 = min(max(x1i, 0), Wi - 1);
        const int cy0 = min(max(y0, 0), Hi - 1), cy1 = min(max(y1i, 0), Hi - 1);
        const float wc[4] = {(1.f-lx)*(1.f-ly)*vx0*vy0*wap, lx*(1.f-ly)*vx1*vy0*wap,
                             (1.f-lx)*ly*vx0*vy1*wap,       lx*ly*vx1*vy1*wap};
        const int idx[4] = {s + cy0*Wi + cx0, s + cy0*Wi + cx1,
                            s + cy1*Wi + cx0, s + cy1*Wi + cx1};
#pragma unroll
        for (int c = 0; c < 4; ++c) {
            const uint4 g = *(const uint4*)(vbase + (size_t)idx[c] * D);
            const float w = wc[c];
            acc[0] = fmaf(w, __uint_as_float(g.x << 16),          acc[0]);
            acc[1] = fmaf(w, __uint_as_float(g.x & 0xffff0000u),  acc[1]);
            acc[2] = fmaf(w, __uint_as_float(g.y << 16),          acc[2]);
            acc[3] = fmaf(w, __uint_as_float(g.y & 0xffff0000u),  acc[3]);
            acc[4] = fmaf(w, __uint_as_float(g.z << 16),          acc[4]);
            acc[5] = fmaf(w, __uint_as_float(g.z & 0xffff0000u),  acc[5]);
            acc[6] = fmaf(w, __uint_as_float(g.w << 16),          acc[6]);
            acc[7] = fmaf(w, __uint_as_float(g.w & 0xffff0000u),  acc[7]);
        }
    }
    uint4 o;
    o.x = pk2(acc[0], acc[1]); o.y = pk2(acc[2], acc[3]);
    o.z = pk2(acc[4], acc[5]); o.w = pk2(acc[6], acc[7]);
    *(uint4*)(out + (size_t)row * D + ch) = o;
}

// ---------------------------------------------------------------------
// out = LayerNorm(a + b) * g + beta over D=256. ONE WAVE per row.
// ---------------------------------------------------------------------
__global__ __launch_bounds__(256) void add_ln(const float* a, const float* b,
                                              const float* __restrict__ g,
                                              const float* __restrict__ be,
                                              const float* __restrict__ pos,
                                              float* out, unsigned short* outb)
{
    const int lane = threadIdx.x & 63;
    const int row  = blockIdx.x * 4 + (threadIdx.x >> 6);
    if (row >= NROWS) return;
    const size_t base = (size_t)row * D + (lane << 2);
    const float4 av = *(const float4*)(a + base);
    const float4 bv = *(const float4*)(b + base);
    float4 v = make_float4(av.x + bv.x, av.y + bv.y, av.z + bv.z, av.w + bv.w);
    float s = v.x + v.y + v.z + v.w;
#pragma unroll
    for (int off = 1; off < 64; off <<= 1) s += __shfl_xor(s, off);
    const float mean = s * (1.f / 256.f);
    const float4 d = make_float4(v.x - mean, v.y - mean, v.z - mean, v.w - mean);
    float q = d.x*d.x + d.y*d.y + d.z*d.z + d.w*d.w;
#pragma unroll
    for (int off = 1; off < 64; off <<= 1) q += __shfl_xor(q, off);
    const float rstd = rsqrtf(q * (1.f / 256.f) + 1e-5f);
    const float4 gv = *(const float4*)(g  + (lane << 2));
    const float4 bev = *(const float4*)(be + (lane << 2));
    float4 o;
    o.x = d.x * rstd * gv.x + bev.x;
    o.y = d.y * rstd * gv.y + bev.y;
    o.z = d.z * rstd * gv.z + bev.z;
    o.w = d.w * rstd * gv.w + bev.w;
    *(float4*)(out + base) = o;
    if (outb) {
        float4 p = make_float4(0.f, 0.f, 0.f, 0.f);
        if (pos) p = *(const float4*)(pos + base);
        uint2 u;
        u.x = pk2(o.x + p.x, o.y + p.y);
        u.y = pk2(o.z + p.z, o.w + p.w);
        *(uint2*)(outb + base) = u;
    }
}

// ---------------------------------------------------------------------
// text K/V projections + text passthrough output (fused).
// 40 blocks, one per text row; block covers 256 channels.
// ---------------------------------------------------------------------
__global__ __launch_bounds__(256) void text_kv(const float* __restrict__ text,
                                               const float* __restrict__ ipw,
                                               const float* __restrict__ ipb,
                                               float* __restrict__ kh,
                                               float* __restrict__ vh,
                                               float* __restrict__ outtxt)
{
    __shared__ float ts[D];
    const int row = blockIdx.x, t = threadIdx.x;
    const float tv = text[(size_t)row * D + t];
    ts[t] = tv;
    outtxt[(size_t)row * D + t] = tv;
    __syncthreads();
    const float* wk = ipw + (size_t)(D + t) * D;
    const float* wv = ipw + (size_t)(2 * D + t) * D;
    float sk = ipb[D + t], sv = ipb[2 * D + t];
    for (int k = 0; k < D; ++k) {
        sk = fmaf(ts[k], wk[k], sk);
        sv = fmaf(ts[k], wv[k], sv);
    }
    kh[(size_t)row * D + t] = sk;
    vh[(size_t)row * D + t] = sv;
}

// ---------------------------------------------------------------------
// cross-attention to text, v2: softmax once per score via half-wave
// shuffle reduction; probs distributed to PV loop via __shfl (no LDS
// round-trip, single barrier). ctx written as bf16.
// ---------------------------------------------------------------------
__global__ __launch_bounds__(256) void text_attn(const float* __restrict__ qh,
                                                 const float* __restrict__ kh,
                                                 const float* __restrict__ vh,
                                                 unsigned short* __restrict__ ctx)
{
    __shared__ float qs[D];
    const int row = blockIdx.x, t = threadIdx.x;
    const int b = row / LQ;
    const int h = t >> 5, d = t & 31;
    const int lane = t & 63;
    qs[t] = qh[(size_t)row * D + t];
    __syncthreads();
    // scores: lanes d<20 compute the (h, k=d) dot over 32 dims
    float sc = -1e30f;
    if (d < LT) {
        const float4* kr = (const float4*)(kh + (size_t)(b * LT + d) * D + h * HDIM);
        const float4* qq = (const float4*)(qs + h * HDIM);
        float s = 0.f;
#pragma unroll
        for (int i = 0; i < 8; ++i) {
            const float4 kv = kr[i], qv = qq[i];
            s = fmaf(qv.x, kv.x, s); s = fmaf(qv.y, kv.y, s);
            s = fmaf(qv.z, kv.z, s); s = fmaf(qv.w, kv.w, s);
        }
        sc = s * 0.17677669529663687f;   // 1/sqrt(32)
    }
    // softmax across the 32-lane half-wave (xor offsets < 32 stay in half)
    float mx = sc;
#pragma unroll
    for (int off = 1; off < 32; off <<= 1) mx = fmaxf(mx, __shfl_xor(mx, off));
    const float e = (d < LT) ? __expf(sc - mx) : 0.f;
    float sm = e;
#pragma unroll
    for (int off = 1; off < 32; off <<= 1) sm += __shfl_xor(sm, off);
    const float pr = e * (1.f / sm);
    // PV: o = sum_k prob(h,k) * vh[(b*LT+k)*D + t]; prob pulled by shuffle
    // from lane (lane&32)|k of this wave (that lane's d==k, same head).
    const float* vb = vh + (size_t)b * LT * D + t;
    float o0 = 0.f, o1 = 0.f;
#pragma unroll
    for (int k = 0; k < LT; k += 2) {
        const float p0 = __shfl(pr, (lane & 32) | k);
        const float p1 = __shfl(pr, (lane & 32) | (k + 1));
        o0 = fmaf(p0, vb[(size_t)k * D], o0);
        o1 = fmaf(p1, vb[(size_t)(k + 1) * D], o1);
    }
    ctx[(size_t)row * D + t] = f2b(o0 + o1);
}

// =====================================================================
extern "C" void kernel_launch(void* const* d_in, const int* in_sizes, int n_in,
                              void* d_out, int out_size, void* d_ws, size_t ws_size,
                              hipStream_t stream)
{
    const float* src  = (const float*)d_in[0];
    const float* pos  = (const float*)d_in[1];
    const float* refp = (const float*)d_in[2];
    const float* text = (const float*)d_in[5];
    const float* so_w = (const float*)d_in[7];
    const float* so_b = (const float*)d_in[8];
    const float* aw_w = (const float*)d_in[9];
    const float* aw_b = (const float*)d_in[10];
    const float* vp_w = (const float*)d_in[11];
    const float* vp_b = (const float*)d_in[12];
    const float* op_w = (const float*)d_in[13];
    const float* op_b = (const float*)d_in[14];
    const float* ln1g = (const float*)d_in[15];
    const float* ln1b = (const float*)d_in[16];
    const float* ipw  = (const float*)d_in[17];
    const float* ipb  = (const float*)d_in[18];
    const float* mow  = (const float*)d_in[19];
    const float* mob  = (const float*)d_in[20];
    const float* ln3g = (const float*)d_in[21];
    const float* ln3b = (const float*)d_in[22];
    const float* l1w  = (const float*)d_in[23];
    const float* l1b  = (const float*)d_in[24];
    const float* l2w  = (const float*)d_in[25];
    const float* l2b  = (const float*)d_in[26];
    const float* ln2g = (const float*)d_in[27];
    const float* ln2b = (const float*)d_in[28];

    float* ws = (float*)d_ws;
    float*          oa     = ws;
    unsigned short* srcb   = (unsigned short*)(ws + SFL + SFL / 2);
    unsigned short* mscb   = srcb;
    unsigned short* qbf    = (unsigned short*)(ws + 2 * SFL);
    unsigned short* valb   = (unsigned short*)(ws + 2 * SFL + SFL / 2);
    float*          gen32  = ws + 3 * SFL;
    float*          x12    = ws + 4 * SFL;
    unsigned short* wb     = (unsigned short*)(ws + 5 * SFL);
    unsigned short* hidden = (unsigned short*)ws;   // N x 1024 bf16 overlays [0,2.0)

    unsigned short* wb_vp = wb;
    unsigned short* wb_so = wb + 65536;             // so(256 rows) then aw(128 rows)
    unsigned short* wb_aw = wb + 131072;
    unsigned short* wb_op = wb + 163840;
    unsigned short* wb_wq = wb + 229376;
    unsigned short* wb_mo = wb + 294912;
    unsigned short* wb_l1 = wb + 360448;
    unsigned short* wb_l2 = wb + 622592;            // end 884736 shorts
    float* kvk  = ws + 5 * SFL + 442368;
    float* kvv  = kvk + (size_t)BB * LT * D;
    float* sobc = kvv + (size_t)BB * LT * D;

    const int M = NROWS;
    const int gx = (M + 127) / 128;                 // 316
    const dim3 blk(256);
    const int n4 = (int)(SFL / 4);
    const int vgrid = (n4 + 255) / 256;
    const int dgrid = (M + 7) / 8;
    const int lgrid = (M + 3) / 4;

    // 0. weight casts
    W8 w8;
    w8.s[0] = vp_w; w8.d[0] = wb_vp; w8.n[0] = 65536;
    w8.s[1] = so_w; w8.d[1] = wb_so; w8.n[1] = 65536;
    w8.s[2] = aw_w; w8.d[2] = wb_aw; w8.n[2] = 32768;
    w8.s[3] = op_w; w8.d[3] = wb_op; w8.n[3] = 65536;
    w8.s[4] = ipw;  w8.d[4] = wb_wq; w8.n[4] = 65536;
    w8.s[5] = mow;  w8.d[5] = wb_mo; w8.n[5] = 65536;
    w8.s[6] = l1w;  w8.d[6] = wb_l1; w8.n[6] = 262144;
    w8.s[7] = l2w;  w8.d[7] = wb_l2; w8.n[7] = 262144;
    cast_w8<<<dim3(128, 8), blk, 0, stream>>>(w8);
    cat_bias<<<dim3(1), dim3(384), 0, stream>>>(so_b, aw_b, sobc);
    // 1. srcb = bf16(src), qbf = bf16(src+pos)
    cast_pair<<<dim3(vgrid), blk, 0, stream>>>((const float4*)src, (const float4*)pos,
                                               (ushort4*)srcb, (ushort4*)qbf, n4);
    // 2. value = src @ vp^T + b -> bf16
    gemm_mfma<<<dim3(gx, 2), blk, 0, stream>>>(srcb, wb_vp, vp_b, nullptr, valb, M, 256, 256, 0);
    // 3. merged offs+logits = q @ [so;aw]^T + b -> oa fp32 (N x 384)
    gemm_mfma<<<dim3(gx, 3), blk, 0, stream>>>(qbf, wb_so, sobc, oa, nullptr, M, 384, 256, 0);
    // 4. deformable sampling (softmax fused) -> mscore bf16
    msdeform<<<dim3(dgrid), blk, 0, stream>>>(valb, oa, refp, mscb);
    // 5. ms = mscore @ op^T + b -> fp32
    gemm_mfma<<<dim3(gx, 2), blk, 0, stream>>>(mscb, wb_op, op_b, gen32, nullptr, M, 256, 256, 0);
    // 6. x1 = LN(src + ms) -> x12; q2 = bf16(x1 + pos) -> qbf (fused)
    add_ln<<<dim3(lgrid), blk, 0, stream>>>(src, gen32, ln1g, ln1b, pos, x12, qbf);
    // 7. text K/V + text passthrough out (fused)
    float* outx = (float*)d_out;
    text_kv<<<dim3(BB * LT), blk, 0, stream>>>(text, ipw, ipb, kvk, kvv, outx + SFL);
    // 8. qh = q2 @ wq^T + bq -> fp32
    gemm_mfma<<<dim3(gx, 2), blk, 0, stream>>>(qbf, wb_wq, ipb, gen32, nullptr, M, 256, 256, 0);
    // 9. ctx = attn(qh, K, V) -> bf16 (qbf reused)
    text_attn<<<dim3(M), blk, 0, stream>>>(gen32, kvk, kvv, qbf);
    // 10. mha = ctx @ mow^T + b -> fp32
    gemm_mfma<<<dim3(gx, 2), blk, 0, stream>>>(qbf, wb_mo, mob, gen32, nullptr, M, 256, 256, 0);
    // 11. x2 = LN(x1 + mha) -> x12 in-place; bf16 copy -> qbf
    add_ln<<<dim3(lgrid), blk, 0, stream>>>(x12, gen32, ln3g, ln3b, nullptr, x12, qbf);
    // 12. hidden = relu(x2 @ l1^T + b) -> bf16
    gemm_mfma<<<dim3(gx, 8), blk, 0, stream>>>(qbf, wb_l1, l1b, nullptr, hidden, M, 1024, 256, 1);
    // 13. ffn = hidden @ l2^T + b -> d_out (fp32 scratch)
    gemm_mfma<<<dim3(gx, 2), blk, 0, stream>>>(hidden, wb_l2, l2b, outx, nullptr, M, 256, 1024, 0);
    // 14. x3 = LN(x2 + ffn) -> d_out
    add_ln<<<dim3(lgrid), blk, 0, stream>>>(x12, outx, ln2g, ln2b, nullptr, outx, nullptr);
}

// Round 6
// 694.311 us; speedup vs baseline: 2.8568x; 1.0896x over previous
//
#include <hip/hip_runtime.h>
#include <math.h>

// ---------------- problem constants ----------------
#define D     256
#define NH    8
#define HDIM  32
#define NL    4
#define NPT   4
#define DFF   1024
#define BB    2
#define LT    20
#define LQ    20197
#define NROWS (BB*LQ)                 // 40394
#define SFL   ((size_t)NROWS * D)     // floats per N x 256 buffer

typedef __attribute__((ext_vector_type(8))) short bf16x8;
typedef __attribute__((ext_vector_type(4))) float f32x4;

__device__ __forceinline__ unsigned short f2b(float f) {
    unsigned int u = __float_as_uint(f);
    unsigned int r = (u + 0x7FFFu + ((u >> 16) & 1u)) >> 16;   // RNE
    return (unsigned short)r;
}
__device__ __forceinline__ float b2f(unsigned short u) {
    return __uint_as_float((unsigned int)u << 16);
}
__device__ __forceinline__ unsigned int pk2(float a, float b) {
    return (unsigned int)f2b(a) | ((unsigned int)f2b(b) << 16);
}

#define GLDS16(g, l) __builtin_amdgcn_global_load_lds( \
    (const __attribute__((address_space(1))) unsigned int*)(g), \
    (__attribute__((address_space(3))) unsigned int*)(l), 16, 0, 0)

// =====================================================================
// bf16 MFMA GEMM:  C[M,Nout] = A[M,K](bf16) @ W[Nout,K](bf16)^T + bias
// 128x128 tile, BK=32, 4 waves (2x2 of 64x64), mfma_f32_16x16x32_bf16.
// Output fp32 (Cf) or bf16 (Cb, with optional relu). Nout%128==0, K%32==0.
// =====================================================================
__global__ __launch_bounds__(256) void gemm_mfma(const unsigned short* __restrict__ A,
                                                 const unsigned short* __restrict__ W,
                                                 const float* __restrict__ bias,
                                                 float* __restrict__ Cf,
                                                 unsigned short* __restrict__ Cb,
                                                 int M, int Nout, int K, int relu)
{
    __shared__ __align__(16) unsigned short As[128 * 32];
    __shared__ __align__(16) unsigned short Ws[128 * 32];
    const int tid  = threadIdx.x;
    const int wave = tid >> 6, lane = tid & 63;
    const int row0 = blockIdx.x * 128, n0 = blockIdx.y * 128;
    const int wm = (wave >> 1) * 64, wn = (wave & 1) * 64;

    const int srow = (wave << 5) + (lane >> 2);
    const int kcol = (lane & 3) << 3;
    const int ar0 = min(row0 + srow,      M - 1);
    const int ar1 = min(row0 + srow + 16, M - 1);
    const unsigned short* Ap0 = A + (size_t)ar0 * K + kcol;
    const unsigned short* Ap1 = A + (size_t)ar1 * K + kcol;
    const unsigned short* Wp0 = W + (size_t)(n0 + srow) * K + kcol;
    const unsigned short* Wp1 = W + (size_t)(n0 + srow + 16) * K + kcol;
    unsigned short* lA0 = &As[(wave << 10)];
    unsigned short* lA1 = &As[(wave << 10) + 512];
    unsigned short* lW0 = &Ws[(wave << 10)];
    unsigned short* lW1 = &Ws[(wave << 10) + 512];

    f32x4 acc[4][4];
#pragma unroll
    for (int i = 0; i < 4; ++i)
#pragma unroll
        for (int j = 0; j < 4; ++j)
#pragma unroll
            for (int r = 0; r < 4; ++r) acc[i][j][r] = 0.f;

    const int fr = lane & 15;
    const int fk = (lane >> 4) << 3;

    for (int k0 = 0; k0 < K; k0 += 32) {
        GLDS16(Ap0 + k0, lA0);
        GLDS16(Ap1 + k0, lA1);
        GLDS16(Wp0 + k0, lW0);
        GLDS16(Wp1 + k0, lW1);
        __syncthreads();
        bf16x8 af[4], wf[4];
#pragma unroll
        for (int t = 0; t < 4; ++t) {
            af[t] = *(const bf16x8*)&As[(wm + t * 16 + fr) * 32 + fk];
            wf[t] = *(const bf16x8*)&Ws[(wn + t * 16 + fr) * 32 + fk];
        }
#pragma unroll
        for (int i = 0; i < 4; ++i)
#pragma unroll
            for (int j = 0; j < 4; ++j)
                acc[i][j] = __builtin_amdgcn_mfma_f32_16x16x32_bf16(af[i], wf[j], acc[i][j], 0, 0, 0);
        __syncthreads();
    }

    const int rq = (lane >> 4) << 2;
    const int cq = lane & 15;
#pragma unroll
    for (int mt = 0; mt < 4; ++mt) {
#pragma unroll
        for (int r = 0; r < 4; ++r) {
            const int row = row0 + wm + mt * 16 + rq + r;
            if (row < M) {
#pragma unroll
                for (int nt = 0; nt < 4; ++nt) {
                    const int c = n0 + wn + nt * 16 + cq;
                    float v = acc[mt][nt][r] + bias[c];
                    if (relu) v = fmaxf(v, 0.f);
                    if (Cb) Cb[(size_t)row * Nout + c] = f2b(v);
                    else    Cf[(size_t)row * Nout + c] = v;
                }
            }
        }
    }
}

// ---------------------------------------------------------------------
// batched fp32 -> bf16 weight cast (8 segments)
// ---------------------------------------------------------------------
struct W8 {
    const float* s[8];
    unsigned short* d[8];
    int n[8];
};
__global__ __launch_bounds__(256) void cast_w8(W8 w)
{
    const int seg = blockIdx.y;
    const int n = w.n[seg];
    const float* s = w.s[seg];
    unsigned short* d = w.d[seg];
    for (int i = blockIdx.x * 256 + threadIdx.x; i < n; i += gridDim.x * 256)
        d[i] = f2b(s[i]);
}

// concat so_b(256) + aw_b(128) -> o(384)
__global__ __launch_bounds__(384) void cat_bias(const float* __restrict__ sb,
                                                const float* __restrict__ ab,
                                                float* __restrict__ o)
{
    const int t = threadIdx.x;
    o[t] = (t < 256) ? sb[t] : ab[t - 256];
}

// srcb = bf16(src); qbf = bf16(src + pos)    (one pass)
__global__ __launch_bounds__(256) void cast_pair(const float4* __restrict__ src,
                                                 const float4* __restrict__ pos,
                                                 ushort4* __restrict__ srcb,
                                                 ushort4* __restrict__ qbf, int n4)
{
    const int i = blockIdx.x * 256 + threadIdx.x;
    if (i < n4) {
        const float4 s = src[i], p = pos[i];
        srcb[i] = make_ushort4(f2b(s.x), f2b(s.y), f2b(s.z), f2b(s.w));
        qbf[i]  = make_ushort4(f2b(s.x + p.x), f2b(s.y + p.y), f2b(s.z + p.z), f2b(s.w + p.w));
    }
}

// ---------------------------------------------------------------------
// multi-scale deformable sampling v4.
// 2 queries per wave; 4 lanes per head, each lane owns 8 channels (16B bf16).
// Softmax over the 16 attention logits fused in (group-of-4 shuffle).
// oa layout: N x 384 row-major: [0:256) sampling offsets, [256:384) logits.
// ---------------------------------------------------------------------
__global__ __launch_bounds__(256) void msdeform(const unsigned short* __restrict__ value,
                                                const float* __restrict__ oa,
                                                const float* __restrict__ refp,
                                                unsigned short* __restrict__ out)
{
    const int Hs[4]  = {100, 50, 25, 13};
    const int Wsd[4] = {152, 76, 38, 19};
    const int St[4]  = {0, 15200, 19000, 19950};
    const int tid  = threadIdx.x;
    const int lane = tid & 63;
    const int row  = blockIdx.x * 8 + ((tid >> 6) << 1) + (lane >> 5);
    if (row >= NROWS) return;
    const int b   = row / LQ;
    const int sub = lane & 31;
    const int h   = sub >> 2;
    const int j   = sub & 3;
    const int ch  = (h << 5) + (j << 3);
    const unsigned short* vbase = value + (size_t)b * LQ * D + ch;

    const float* orow = oa + (size_t)row * 384;
    const float4 o0 = *(const float4*)(orow + (h << 5) + (j << 3));
    const float4 o1 = *(const float4*)(orow + (h << 5) + (j << 3) + 4);
    const float oxr[4] = {o0.x, o0.z, o1.x, o1.z};
    const float oyr[4] = {o0.y, o0.w, o1.y, o1.w};
    const float4 lg = *(const float4*)(orow + 256 + (h << 4) + (j << 2));
    float mx = fmaxf(fmaxf(lg.x, lg.y), fmaxf(lg.z, lg.w));
    mx = fmaxf(mx, __shfl_xor(mx, 1));
    mx = fmaxf(mx, __shfl_xor(mx, 2));
    const float e0 = __expf(lg.x - mx), e1 = __expf(lg.y - mx);
    const float e2 = __expf(lg.z - mx), e3 = __expf(lg.w - mx);
    float sm = e0 + e1 + e2 + e3;
    sm += __shfl_xor(sm, 1);
    sm += __shfl_xor(sm, 2);
    const float inv = 1.f / sm;
    const float pr[4] = {e0 * inv, e1 * inv, e2 * inv, e3 * inv};
    const float4 r01 = *(const float4*)(refp + (size_t)row * 8);
    const float4 r23 = *(const float4*)(refp + (size_t)row * 8 + 4);
    const float rxr[4] = {r01.x, r01.z, r23.x, r23.z};
    const float ryr[4] = {r01.y, r01.w, r23.y, r23.w};

    float acc[8] = {0.f,0.f,0.f,0.f,0.f,0.f,0.f,0.f};
    const int gb = lane & ~3;
#pragma unroll
    for (int t = 0; t < 16; ++t) {
        const int l = t >> 2;
        const int Wi = Wsd[l], Hi = Hs[l], s = St[l];
        const float Wf = (float)Wi, Hf = (float)Hi;
        const int srcl = gb + (t >> 2);
        const float ox  = __shfl(oxr[t & 3], srcl);
        const float oy  = __shfl(oyr[t & 3], srcl);
        const float wap = __shfl(pr[t & 3],  srcl);
        const float x = (rxr[l] + ox / Wf) * Wf - 0.5f;
        const float y = (ryr[l] + oy / Hf) * Hf - 0.5f;
        const float x0f = floorf(x), y0f = floorf(y);
        const float lx = x - x0f, ly = y - y0f;
        const int x0 = (int)x0f, y0 = (int)y0f;
        const int x1i = x0 + 1, y1i = y0 + 1;
        const float vx0 = (x0  >= 0 && x0  < Wi) ? 1.f : 0.f;
        const float vx1 = (x1i >= 0 && x1i < Wi) ? 1.f : 0.f;
        const float vy0 = (y0  >= 0 && y0  < Hi) ? 1.f : 0.f;
        const float vy1 = (y1i >= 0 && y1i < Hi) ? 1.f : 0.f;
        const int cx0 = min(max(x0, 0), Wi - 1), cx1 = min(max(x1i, 0), Wi - 1);
        const int cy0 = min(max(y0, 0), Hi - 1), cy1 = min(max(y1i, 0), Hi - 1);
        const float wc[4] = {(1.f-lx)*(1.f-ly)*vx0*vy0*wap, lx*(1.f-ly)*vx1*vy0*wap,
                             (1.f-lx)*ly*vx0*vy1*wap,       lx*ly*vx1*vy1*wap};
        const int idx[4] = {s + cy0*Wi + cx0, s + cy0*Wi + cx1,
                            s + cy1*Wi + cx0, s + cy1*Wi + cx1};
#pragma unroll
        for (int c = 0; c < 4; ++c) {
            const uint4 g = *(const uint4*)(vbase + (size_t)idx[c] * D);
            const float w = wc[c];
            acc[0] = fmaf(w, __uint_as_float(g.x << 16),          acc[0]);
            acc[1] = fmaf(w, __uint_as_float(g.x & 0xffff0000u),  acc[1]);
            acc[2] = fmaf(w, __uint_as_float(g.y << 16),          acc[2]);
            acc[3] = fmaf(w, __uint_as_float(g.y & 0xffff0000u),  acc[3]);
            acc[4] = fmaf(w, __uint_as_float(g.z << 16),          acc[4]);
            acc[5] = fmaf(w, __uint_as_float(g.z & 0xffff0000u),  acc[5]);
            acc[6] = fmaf(w, __uint_as_float(g.w << 16),          acc[6]);
            acc[7] = fmaf(w, __uint_as_float(g.w & 0xffff0000u),  acc[7]);
        }
    }
    uint4 o;
    o.x = pk2(acc[0], acc[1]); o.y = pk2(acc[2], acc[3]);
    o.z = pk2(acc[4], acc[5]); o.w = pk2(acc[6], acc[7]);
    *(uint4*)(out + (size_t)row * D + ch) = o;
}

// ---------------------------------------------------------------------
// out = LayerNorm(a + b) * g + beta over D=256. ONE WAVE per row.
// ---------------------------------------------------------------------
__global__ __launch_bounds__(256) void add_ln(const float* a, const float* b,
                                              const float* __restrict__ g,
                                              const float* __restrict__ be,
                                              const float* __restrict__ pos,
                                              float* out, unsigned short* outb)
{
    const int lane = threadIdx.x & 63;
    const int row  = blockIdx.x * 4 + (threadIdx.x >> 6);
    if (row >= NROWS) return;
    const size_t base = (size_t)row * D + (lane << 2);
    const float4 av = *(const float4*)(a + base);
    const float4 bv = *(const float4*)(b + base);
    float4 v = make_float4(av.x + bv.x, av.y + bv.y, av.z + bv.z, av.w + bv.w);
    float s = v.x + v.y + v.z + v.w;
#pragma unroll
    for (int off = 1; off < 64; off <<= 1) s += __shfl_xor(s, off);
    const float mean = s * (1.f / 256.f);
    const float4 d = make_float4(v.x - mean, v.y - mean, v.z - mean, v.w - mean);
    float q = d.x*d.x + d.y*d.y + d.z*d.z + d.w*d.w;
#pragma unroll
    for (int off = 1; off < 64; off <<= 1) q += __shfl_xor(q, off);
    const float rstd = rsqrtf(q * (1.f / 256.f) + 1e-5f);
    const float4 gv = *(const float4*)(g  + (lane << 2));
    const float4 bev = *(const float4*)(be + (lane << 2));
    float4 o;
    o.x = d.x * rstd * gv.x + bev.x;
    o.y = d.y * rstd * gv.y + bev.y;
    o.z = d.z * rstd * gv.z + bev.z;
    o.w = d.w * rstd * gv.w + bev.w;
    *(float4*)(out + base) = o;
    if (outb) {
        float4 p = make_float4(0.f, 0.f, 0.f, 0.f);
        if (pos) p = *(const float4*)(pos + base);
        uint2 u;
        u.x = pk2(o.x + p.x, o.y + p.y);
        u.y = pk2(o.z + p.z, o.w + p.w);
        *(uint2*)(outb + base) = u;
    }
}

// ---------------------------------------------------------------------
// text K/V projections + text passthrough output (fused).
// ---------------------------------------------------------------------
__global__ __launch_bounds__(256) void text_kv(const float* __restrict__ text,
                                               const float* __restrict__ ipw,
                                               const float* __restrict__ ipb,
                                               float* __restrict__ kh,
                                               float* __restrict__ vh,
                                               float* __restrict__ outtxt)
{
    __shared__ float ts[D];
    const int row = blockIdx.x, t = threadIdx.x;
    const float tv = text[(size_t)row * D + t];
    ts[t] = tv;
    outtxt[(size_t)row * D + t] = tv;
    __syncthreads();
    const float* wk = ipw + (size_t)(D + t) * D;
    const float* wv = ipw + (size_t)(2 * D + t) * D;
    float sk = ipb[D + t], sv = ipb[2 * D + t];
    for (int k = 0; k < D; ++k) {
        sk = fmaf(ts[k], wk[k], sk);
        sv = fmaf(ts[k], wv[k], sv);
    }
    kh[(size_t)row * D + t] = sk;
    vh[(size_t)row * D + t] = sv;
}

// ---------------------------------------------------------------------
// cross-attention to text, v3: 8 query rows per block; V + 8 q-rows
// staged in LDS once; K-fragment and V-column hoisted to registers and
// reused across all 8 rows (kills the per-row L2 re-reads that made v2
// latency-bound). Softmax via half-wave shuffle. ctx written as bf16.
// grid: (ceil(LQ/8), B)
// ---------------------------------------------------------------------
__global__ __launch_bounds__(256) void text_attn(const float* __restrict__ qh,
                                                 const float* __restrict__ kh,
                                                 const float* __restrict__ vh,
                                                 unsigned short* __restrict__ ctx)
{
    __shared__ float vs[LT * D];      // 20 KB
    __shared__ float qs[8][D];        // 8 KB
    const int b  = blockIdx.y;
    const int q0 = blockIdx.x * 8;
    const int t  = threadIdx.x;
    const int nr = min(8, LQ - q0);

    // stage V (coalesced float4) and the 8 q-rows
    {
        const float4* vsrc = (const float4*)(vh + (size_t)b * LT * D);
        float4* vdst = (float4*)vs;
#pragma unroll
        for (int i = 0; i < 5; ++i) vdst[t + 256 * i] = vsrc[t + 256 * i];
        for (int r = 0; r < nr; ++r)
            qs[r][t] = qh[((size_t)b * LQ + q0 + r) * D + t];
    }
    __syncthreads();

    const int h = t >> 5, d = t & 31;
    const int lane = t & 63;
    // K fragment for this lane's (h, k=d) score — from global, once per block
    float kf[32];
    if (d < LT) {
        const float4* kr = (const float4*)(kh + (size_t)(b * LT + d) * D + h * HDIM);
#pragma unroll
        for (int i = 0; i < 8; ++i) {
            const float4 kv = kr[i];
            kf[4*i] = kv.x; kf[4*i+1] = kv.y; kf[4*i+2] = kv.z; kf[4*i+3] = kv.w;
        }
    }
    // V column t for all k — from LDS, once per block
    float vv[LT];
#pragma unroll
    for (int k = 0; k < LT; ++k) vv[k] = vs[k * D + t];

    for (int r = 0; r < nr; ++r) {
        float sc = -1e30f;
        if (d < LT) {
            const float4* qq = (const float4*)(qs[r] + h * HDIM);
            float s = 0.f;
#pragma unroll
            for (int i = 0; i < 8; ++i) {
                const float4 qv = qq[i];
                s = fmaf(qv.x, kf[4*i],   s); s = fmaf(qv.y, kf[4*i+1], s);
                s = fmaf(qv.z, kf[4*i+2], s); s = fmaf(qv.w, kf[4*i+3], s);
            }
            sc = s * 0.17677669529663687f;   // 1/sqrt(32)
        }
        float mx = sc;
#pragma unroll
        for (int off = 1; off < 32; off <<= 1) mx = fmaxf(mx, __shfl_xor(mx, off));
        const float e = (d < LT) ? __expf(sc - mx) : 0.f;
        float sm = e;
#pragma unroll
        for (int off = 1; off < 32; off <<= 1) sm += __shfl_xor(sm, off);
        const float pr = e * (1.f / sm);
        float o0 = 0.f, o1 = 0.f;
#pragma unroll
        for (int k = 0; k < LT; k += 2) {
            const float p0 = __shfl(pr, (lane & 32) | k);
            const float p1 = __shfl(pr, (lane & 32) | (k + 1));
            o0 = fmaf(p0, vv[k],     o0);
            o1 = fmaf(p1, vv[k + 1], o1);
        }
        ctx[((size_t)b * LQ + q0 + r) * D + t] = f2b(o0 + o1);
    }
}

// =====================================================================
extern "C" void kernel_launch(void* const* d_in, const int* in_sizes, int n_in,
                              void* d_out, int out_size, void* d_ws, size_t ws_size,
                              hipStream_t stream)
{
    const float* src  = (const float*)d_in[0];
    const float* pos  = (const float*)d_in[1];
    const float* refp = (const float*)d_in[2];
    const float* text = (const float*)d_in[5];
    const float* so_w = (const float*)d_in[7];
    const float* so_b = (const float*)d_in[8];
    const float* aw_w = (const float*)d_in[9];
    const float* aw_b = (const float*)d_in[10];
    const float* vp_w = (const float*)d_in[11];
    const float* vp_b = (const float*)d_in[12];
    const float* op_w = (const float*)d_in[13];
    const float* op_b = (const float*)d_in[14];
    const float* ln1g = (const float*)d_in[15];
    const float* ln1b = (const float*)d_in[16];
    const float* ipw  = (const float*)d_in[17];
    const float* ipb  = (const float*)d_in[18];
    const float* mow  = (const float*)d_in[19];
    const float* mob  = (const float*)d_in[20];
    const float* ln3g = (const float*)d_in[21];
    const float* ln3b = (const float*)d_in[22];
    const float* l1w  = (const float*)d_in[23];
    const float* l1b  = (const float*)d_in[24];
    const float* l2w  = (const float*)d_in[25];
    const float* l2b  = (const float*)d_in[26];
    const float* ln2g = (const float*)d_in[27];
    const float* ln2b = (const float*)d_in[28];

    float* ws = (float*)d_ws;
    float*          oa     = ws;
    unsigned short* srcb   = (unsigned short*)(ws + SFL + SFL / 2);
    unsigned short* mscb   = srcb;
    unsigned short* qbf    = (unsigned short*)(ws + 2 * SFL);
    unsigned short* valb   = (unsigned short*)(ws + 2 * SFL + SFL / 2);
    float*          gen32  = ws + 3 * SFL;
    float*          x12    = ws + 4 * SFL;
    unsigned short* wb     = (unsigned short*)(ws + 5 * SFL);
    unsigned short* hidden = (unsigned short*)ws;   // N x 1024 bf16 overlays [0,2.0)

    unsigned short* wb_vp = wb;
    unsigned short* wb_so = wb + 65536;             // so(256 rows) then aw(128 rows)
    unsigned short* wb_aw = wb + 131072;
    unsigned short* wb_op = wb + 163840;
    unsigned short* wb_wq = wb + 229376;
    unsigned short* wb_mo = wb + 294912;
    unsigned short* wb_l1 = wb + 360448;
    unsigned short* wb_l2 = wb + 622592;            // end 884736 shorts
    float* kvk  = ws + 5 * SFL + 442368;
    float* kvv  = kvk + (size_t)BB * LT * D;
    float* sobc = kvv + (size_t)BB * LT * D;

    const int M = NROWS;
    const int gx = (M + 127) / 128;                 // 316
    const dim3 blk(256);
    const int n4 = (int)(SFL / 4);
    const int vgrid = (n4 + 255) / 256;
    const int dgrid = (M + 7) / 8;
    const int lgrid = (M + 3) / 4;

    // 0. weight casts
    W8 w8;
    w8.s[0] = vp_w; w8.d[0] = wb_vp; w8.n[0] = 65536;
    w8.s[1] = so_w; w8.d[1] = wb_so; w8.n[1] = 65536;
    w8.s[2] = aw_w; w8.d[2] = wb_aw; w8.n[2] = 32768;
    w8.s[3] = op_w; w8.d[3] = wb_op; w8.n[3] = 65536;
    w8.s[4] = ipw;  w8.d[4] = wb_wq; w8.n[4] = 65536;
    w8.s[5] = mow;  w8.d[5] = wb_mo; w8.n[5] = 65536;
    w8.s[6] = l1w;  w8.d[6] = wb_l1; w8.n[6] = 262144;
    w8.s[7] = l2w;  w8.d[7] = wb_l2; w8.n[7] = 262144;
    cast_w8<<<dim3(128, 8), blk, 0, stream>>>(w8);
    cat_bias<<<dim3(1), dim3(384), 0, stream>>>(so_b, aw_b, sobc);
    // 1. srcb = bf16(src), qbf = bf16(src+pos)
    cast_pair<<<dim3(vgrid), blk, 0, stream>>>((const float4*)src, (const float4*)pos,
                                               (ushort4*)srcb, (ushort4*)qbf, n4);
    // 2. value = src @ vp^T + b -> bf16
    gemm_mfma<<<dim3(gx, 2), blk, 0, stream>>>(srcb, wb_vp, vp_b, nullptr, valb, M, 256, 256, 0);
    // 3. merged offs+logits = q @ [so;aw]^T + b -> oa fp32 (N x 384)
    gemm_mfma<<<dim3(gx, 3), blk, 0, stream>>>(qbf, wb_so, sobc, oa, nullptr, M, 384, 256, 0);
    // 4. deformable sampling (softmax fused) -> mscore bf16
    msdeform<<<dim3(dgrid), blk, 0, stream>>>(valb, oa, refp, mscb);
    // 5. ms = mscore @ op^T + b -> fp32
    gemm_mfma<<<dim3(gx, 2), blk, 0, stream>>>(mscb, wb_op, op_b, gen32, nullptr, M, 256, 256, 0);
    // 6. x1 = LN(src + ms) -> x12; q2 = bf16(x1 + pos) -> qbf (fused)
    add_ln<<<dim3(lgrid), blk, 0, stream>>>(src, gen32, ln1g, ln1b, pos, x12, qbf);
    // 7. text K/V + text passthrough out (fused)
    float* outx = (float*)d_out;
    text_kv<<<dim3(BB * LT), blk, 0, stream>>>(text, ipw, ipb, kvk, kvv, outx + SFL);
    // 8. qh = q2 @ wq^T + bq -> fp32
    gemm_mfma<<<dim3(gx, 2), blk, 0, stream>>>(qbf, wb_wq, ipb, gen32, nullptr, M, 256, 256, 0);
    // 9. ctx = attn(qh, K, V) -> bf16 (qbf reused)
    text_attn<<<dim3((LQ + 7) / 8, BB), blk, 0, stream>>>(gen32, kvk, kvv, qbf);
    // 10. mha = ctx @ mow^T + b -> fp32
    gemm_mfma<<<dim3(gx, 2), blk, 0, stream>>>(qbf, wb_mo, mob, gen32, nullptr, M, 256, 256, 0);
    // 11. x2 = LN(x1 + mha) -> x12 in-place; bf16 copy -> qbf
    add_ln<<<dim3(lgrid), blk, 0, stream>>>(x12, gen32, ln3g, ln3b, nullptr, x12, qbf);
    // 12. hidden = relu(x2 @ l1^T + b) -> bf16
    gemm_mfma<<<dim3(gx, 8), blk, 0, stream>>>(qbf, wb_l1, l1b, nullptr, hidden, M, 1024, 256, 1);
    // 13. ffn = hidden @ l2^T + b -> d_out (fp32 scratch)
    gemm_mfma<<<dim3(gx, 2), blk, 0, stream>>>(hidden, wb_l2, l2b, outx, nullptr, M, 256, 1024, 0);
    // 14. x3 = LN(x2 + ffn) -> d_out
    add_ln<<<dim3(lgrid), blk, 0, stream>>>(x12, outx, ln2g, ln2b, nullptr, outx, nullptr);
}